// Round 2
// baseline (1226.759 us; speedup 1.0000x reference)
//
#include <hip/hip_runtime.h>
#include <hip/hip_bf16.h>

typedef __hip_bfloat16 bf16;
typedef __attribute__((ext_vector_type(8))) short bh8;      // 8 x bf16 bits
typedef __attribute__((ext_vector_type(4))) float f32x4;

#define CDIM 512
#define NDIM 4096
#define HIDD 2048
#define BATCH 8

__device__ __forceinline__ float bf2f(short s) {
    union { unsigned u; float f; } c; c.u = ((unsigned)(unsigned short)s) << 16; return c.f;
}
__device__ __forceinline__ short f2bf(float f) {
    union { __hip_bfloat16 h; short s; } c; c.h = __float2bfloat16(f); return c.s;
}
__device__ __forceinline__ float wsum(float v) {
#pragma unroll
    for (int o = 32; o; o >>= 1) v += __shfl_xor(v, o);
    return v;
}
__device__ __forceinline__ float wmax(float v) {
#pragma unroll
    for (int o = 32; o; o >>= 1) v = fmaxf(v, __shfl_xor(v, o));
    return v;
}

#define GLL(g, l) __builtin_amdgcn_global_load_lds( \
    (const __attribute__((address_space(1))) unsigned int*)(g), \
    (__attribute__((address_space(3))) unsigned int*)(l), 16, 0, 0)

// ---------------------------------------------------------------- GEMM (NT)
// C[M,N] = A(M,K) @ Bt(N,K)^T, row-major bf16, fp32 accum. 128x128 tile, BK=64.
enum { EP_F32_BROW = 0, EP_BF16_BROW = 1, EP_ATTN = 3, EP_BF16_BCOL = 4, EP_OUT = 5 };

template<int MODE>
__global__ __launch_bounds__(256)
void gemm_bt(const bf16* __restrict__ A, int lda, long sA,
             const bf16* __restrict__ Bt, int ldb, long sB,
             void* __restrict__ Cp, int ldc, long sC, int K,
             const float* __restrict__ bias,
             const float* __restrict__ aux1, long sAux1,
             const float* __restrict__ aux2, long sAux2)
{
    __shared__ __align__(16) bf16 As[128 * 64];
    __shared__ __align__(16) bf16 Bs[128 * 64];
    const int bz = blockIdx.z;
    const bf16* Ab = A + (long)bz * sA + (long)blockIdx.y * 128 * lda;
    const bf16* Bb = Bt + (long)bz * sB + (long)blockIdx.x * 128 * ldb;
    const int t = threadIdx.x, lane = t & 63, wid = t >> 6;
    const int wm = wid >> 1, wn = wid & 1, lg = lane >> 4, lr = lane & 15;

    f32x4 acc[4][4];
#pragma unroll
    for (int m = 0; m < 4; ++m)
#pragma unroll
        for (int n = 0; n < 4; ++n) acc[m][n] = (f32x4){0.f, 0.f, 0.f, 0.f};

    for (int kt = 0; kt < K; kt += 64) {
#pragma unroll
        for (int i = 0; i < 4; ++i) {
            int ch = i * 256 + t;
            GLL(Ab + (long)(ch >> 3) * lda + kt + ((ch & 7) << 3), (char*)As + i * 4096 + wid * 1024);
            GLL(Bb + (long)(ch >> 3) * ldb + kt + ((ch & 7) << 3), (char*)Bs + i * 4096 + wid * 1024);
        }
        __syncthreads();
#pragma unroll
        for (int kk = 0; kk < 2; ++kk) {
            bh8 af[4], bfv[4];
#pragma unroll
            for (int m = 0; m < 4; ++m) af[m] = *(const bh8*)(As + (wm * 64 + m * 16 + lr) * 64 + kk * 32 + lg * 8);
#pragma unroll
            for (int n = 0; n < 4; ++n) bfv[n] = *(const bh8*)(Bs + (wn * 64 + n * 16 + lr) * 64 + kk * 32 + lg * 8);
#pragma unroll
            for (int m = 0; m < 4; ++m)
#pragma unroll
                for (int n = 0; n < 4; ++n)
                    acc[m][n] = __builtin_amdgcn_mfma_f32_16x16x32_bf16(af[m], bfv[n], acc[m][n], 0, 0, 0);
        }
        __syncthreads();
    }

    const int gr0 = blockIdx.y * 128 + wm * 64;
    const int gc0 = blockIdx.x * 128 + wn * 64;
#pragma unroll
    for (int m = 0; m < 4; ++m) {
#pragma unroll
        for (int n = 0; n < 4; ++n) {
            const int gc = gc0 + n * 16 + lr;
#pragma unroll
            for (int r = 0; r < 4; ++r) {
                const int gr = gr0 + m * 16 + lg * 4 + r;
                float v = acc[m][n][r];
                if constexpr (MODE == EP_F32_BROW) {
                    ((float*)Cp + (long)bz * sC)[(long)gr * ldc + gc] = v + bias[gr];
                } else if constexpr (MODE == EP_BF16_BROW) {
                    ((bf16*)Cp + (long)bz * sC)[(long)gr * ldc + gc] = __float2bfloat16(v + bias[gr]);
                } else if constexpr (MODE == EP_ATTN) {
                    const float* xg = aux1 + (long)bz * sAux1;   // x[b] (C, N): shortcut
                    const float* zg = aux2 + (long)bz * sAux2;   // z[b] (N)
                    ((float*)Cp + (long)bz * sC)[(long)gr * ldc + gc] = zg[gr] * v + xg[(long)gc * NDIM + gr];
                } else if constexpr (MODE == EP_BF16_BCOL) {
                    ((bf16*)Cp + (long)bz * sC)[(long)gr * ldc + gc] = __float2bfloat16(v + bias[gc]);
                } else { // EP_OUT: out = acc + bias[col] + out (in-place residual)
                    float* op = (float*)Cp;
                    const long idx = (long)gr * ldc + gc;
                    op[idx] = v + bias[gc] + aux1[idx];
                }
            }
        }
    }
}

// ---------------------------------------------------------------- GEMM (TN)
// C[m,n] = sum_k A[k,m]*B[k,n].  A:(K x M) row-major, B:(K x N) row-major.
// Tile 128x128, BK=64. LDS tiles stored [k][col] linear (global_load_lds),
// transpose happens in the fragment reads (scalar b16).
__global__ __launch_bounds__(256)
void gemm_tn(const bf16* __restrict__ A, int lda, long sA,
             const bf16* __restrict__ B, int ldb, long sB,
             bf16* __restrict__ C, int ldc, long sC, int K)
{
    __shared__ __align__(16) short As[64 * 128];
    __shared__ __align__(16) short Bs[64 * 128];
    const int bz = blockIdx.z;
    const bf16* Ab = A + (long)bz * sA + blockIdx.y * 128;
    const bf16* Bb = B + (long)bz * sB + blockIdx.x * 128;
    const int t = threadIdx.x, lane = t & 63, wid = t >> 6;
    const int wm = wid >> 1, wn = wid & 1, lg = lane >> 4, lr = lane & 15;

    f32x4 acc[4][4];
#pragma unroll
    for (int m = 0; m < 4; ++m)
#pragma unroll
        for (int n = 0; n < 4; ++n) acc[m][n] = (f32x4){0.f, 0.f, 0.f, 0.f};

    for (int kt = 0; kt < K; kt += 64) {
#pragma unroll
        for (int i = 0; i < 4; ++i) {
            int ch = i * 256 + t;                       // tile elem16 index
            GLL(Ab + (long)(kt + (ch >> 4)) * lda + ((ch & 15) << 3), (char*)As + i * 4096 + wid * 1024);
            GLL(Bb + (long)(kt + (ch >> 4)) * ldb + ((ch & 15) << 3), (char*)Bs + i * 4096 + wid * 1024);
        }
        __syncthreads();
#pragma unroll
        for (int kk = 0; kk < 2; ++kk) {
            bh8 af[4], bfv[4];
#pragma unroll
            for (int m = 0; m < 4; ++m) {
                const int col = wm * 64 + m * 16 + lr;
#pragma unroll
                for (int u = 0; u < 8; ++u) af[m][u] = As[(kk * 32 + lg * 8 + u) * 128 + col];
            }
#pragma unroll
            for (int n = 0; n < 4; ++n) {
                const int col = wn * 64 + n * 16 + lr;
#pragma unroll
                for (int u = 0; u < 8; ++u) bfv[n][u] = Bs[(kk * 32 + lg * 8 + u) * 128 + col];
            }
#pragma unroll
            for (int m = 0; m < 4; ++m)
#pragma unroll
                for (int n = 0; n < 4; ++n)
                    acc[m][n] = __builtin_amdgcn_mfma_f32_16x16x32_bf16(af[m], bfv[n], acc[m][n], 0, 0, 0);
        }
        __syncthreads();
    }

    const int gr0 = blockIdx.y * 128 + wm * 64;
    const int gc0 = blockIdx.x * 128 + wn * 64;
#pragma unroll
    for (int m = 0; m < 4; ++m)
#pragma unroll
        for (int n = 0; n < 4; ++n) {
            const int gc = gc0 + n * 16 + lr;
#pragma unroll
            for (int r = 0; r < 4; ++r) {
                const int gr = gr0 + m * 16 + lg * 4 + r;
                (C + (long)bz * sC)[(long)gr * ldc + gc] = __float2bfloat16(acc[m][n][r]);
            }
        }
}

// ---------------------------------------------------------------- transpose
// dst (Rd x Cd) bf16, dst[r,c] = src[c,r]; src is (Cd x Rd) row-major f32.
__global__ __launch_bounds__(256)
void k_transpose(const float* __restrict__ src, bf16* __restrict__ dst,
                 int Rd, int Cd, long sSrc, long sDst)
{
    __shared__ float tile[64][65];
    const float* s = src + (long)blockIdx.z * sSrc;
    bf16* d = dst + (long)blockIdx.z * sDst;
    const int r0 = blockIdx.x * 64, c0 = blockIdx.y * 64;
    const int t = threadIdx.x;
#pragma unroll 4
    for (int i = 0; i < 16; ++i) {
        int idx = i * 256 + t;
        int a = idx >> 6, b = idx & 63;
        tile[a][b] = s[(long)(c0 + a) * Rd + r0 + b];
    }
    __syncthreads();
#pragma unroll 4
    for (int i = 0; i < 16; ++i) {
        int idx = i * 256 + t;
        int a = idx >> 6, b = idx & 63;
        d[(long)(r0 + a) * Cd + c0 + b] = __float2bfloat16(tile[b][a]);
    }
}

__global__ void k_cvt_bf16(const float* __restrict__ in, bf16* __restrict__ out, int n) {
    int i = blockIdx.x * 256 + threadIdx.x;
    if (i < n) out[i] = __float2bfloat16(in[i]);
}

__global__ void k_invsc(const float* __restrict__ scale, float* __restrict__ invsc) {
    int j = threadIdx.x;
    invsc[j] = 1.0f / log1pf(expf(scale[j]));   // 1/softplus(scale)
}

__global__ void k_fill(float* o, int n, float v) {
    int i = blockIdx.x * 256 + threadIdx.x; if (i < n) o[i] = v;
}

// ------------------------------------------------- q column-softmax denom
// softmax axis=1: column j of the (N,C) view = stride-CDIM walk of flat buf.
__global__ __launch_bounds__(256)
void k_qcol_partial(const float* __restrict__ qraw, float* __restrict__ qpart) {
    const int j = blockIdx.x * 256 + threadIdx.x;
    const int ic = blockIdx.y, b = blockIdx.z;
    const float* p = qraw + (long)b * (NDIM * CDIM) + (long)ic * 512 * CDIM + j;
    float s = 0.f;
    for (int i = 0; i < 512; ++i) s += expf(p[(long)i * CDIM]);
    qpart[((long)b * 8 + ic) * CDIM + j] = s;
}
__global__ __launch_bounds__(256)
void k_qcol_reduce(const float* __restrict__ qpart, float* __restrict__ qsum) {
    const int idx = blockIdx.x * 256 + threadIdx.x;  // B*C = 4096
    const int b = idx >> 9, j = idx & 511;
    float s = 0.f;
#pragma unroll
    for (int ic = 0; ic < 8; ++ic) s += qpart[((long)b * 8 + ic) * CDIM + j];
    qsum[idx] = s;
}

// q row pass: p=(exp/colsum + 1e-6)/sc, keep ||p||, cube, renorm -> bf16
__global__ __launch_bounds__(256)
void k_qrow(const float* __restrict__ qraw, const float* __restrict__ qsum,
            const float* __restrict__ invsc, bf16* __restrict__ qb)
{
    const long row = (long)blockIdx.x * 4 + (threadIdx.x >> 6);
    const int lane = threadIdx.x & 63;
    const int b = (int)(row >> 12);
    const float* p = qraw + row * CDIM + lane * 8;
    const float* qs = qsum + b * CDIM + lane * 8;
    const float* is = invsc + lane * 8;
    f32x4 v0 = *(const f32x4*)p, v1 = *(const f32x4*)(p + 4);
    f32x4 s0 = *(const f32x4*)qs, s1 = *(const f32x4*)(qs + 4);
    f32x4 i0 = *(const f32x4*)is, i1 = *(const f32x4*)(is + 4);
    float q[8];
#pragma unroll
    for (int k = 0; k < 4; ++k) {
        q[k]     = (expf(v0[k]) / s0[k] + 1e-6f) * i0[k];
        q[k + 4] = (expf(v1[k]) / s1[k] + 1e-6f) * i1[k];
    }
    float s2 = 0.f, s6 = 0.f, q3[8];
#pragma unroll
    for (int k = 0; k < 8; ++k) { s2 += q[k] * q[k]; float c = q[k] * q[k] * q[k]; q3[k] = c; s6 += c * c; }
    s2 = wsum(s2); s6 = wsum(s6);
    const float sc = sqrtf(s2) / sqrtf(s6);
    bh8 o;
#pragma unroll
    for (int k = 0; k < 8; ++k) o[k] = f2bf(q3[k] * sc);
    *(bh8*)(qb + row * CDIM + lane * 8) = o;
}

// k row pass (IN-PLACE, bf16): row softmax (axis=2), /sc, cube, renorm.
__global__ __launch_bounds__(256)
void k_krow(bf16* __restrict__ kb, const float* __restrict__ invsc)
{
    const long row = (long)blockIdx.x * 4 + (threadIdx.x >> 6);
    const int lane = threadIdx.x & 63;
    bh8 v = *(const bh8*)(kb + row * CDIM + lane * 8);
    const float* is = invsc + lane * 8;
    f32x4 i0 = *(const f32x4*)is, i1 = *(const f32x4*)(is + 4);
    float xv[8];
#pragma unroll
    for (int k = 0; k < 8; ++k) xv[k] = bf2f(v[k]);
    float mx = -1e30f;
#pragma unroll
    for (int k = 0; k < 8; ++k) mx = fmaxf(mx, xv[k]);
    mx = wmax(mx);
    float e[8], se = 0.f;
#pragma unroll
    for (int k = 0; k < 8; ++k) { e[k] = expf(xv[k] - mx); se += e[k]; }
    se = wsum(se);
    const float inv = 1.0f / se;
    float q[8];
#pragma unroll
    for (int k = 0; k < 4; ++k) {
        q[k]     = (e[k] * inv + 1e-6f) * i0[k];
        q[k + 4] = (e[k + 4] * inv + 1e-6f) * i1[k];
    }
    float s2 = 0.f, s6 = 0.f, q3[8];
#pragma unroll
    for (int k = 0; k < 8; ++k) { s2 += q[k] * q[k]; float c = q[k] * q[k] * q[k]; q3[k] = c; s6 += c * c; }
    s2 = wsum(s2); s6 = wsum(s6);
    const float sc = sqrtf(s2) / sqrtf(s6);
    bh8 o;
#pragma unroll
    for (int k = 0; k < 8; ++k) o[k] = f2bf(q3[k] * sc);
    *(bh8*)(kb + row * CDIM + lane * 8) = o;
}

// ksum[b,c] = sum_j kb[b,j,c] : two-stage column sum of (N,C) rows.
__global__ __launch_bounds__(256)
void k_colsum_part(const bf16* __restrict__ kb, float* __restrict__ part) {
    const int b = blockIdx.y, jc = blockIdx.x, t = threadIdx.x;
    const bf16* p = kb + (long)b * (NDIM * CDIM) + (long)jc * 512 * CDIM + t * 2;
    float s0 = 0.f, s1 = 0.f;
    for (int j = 0; j < 512; ++j) {
        unsigned u = *(const unsigned*)(p + (long)j * CDIM);
        s0 += bf2f((short)(u & 0xffff));
        s1 += bf2f((short)(u >> 16));
    }
    float* o = part + ((long)b * 8 + jc) * CDIM + t * 2;
    o[0] = s0; o[1] = s1;
}
__global__ __launch_bounds__(256)
void k_colsum_red(const float* __restrict__ part, float* __restrict__ ksum) {
    const int idx = blockIdx.x * 256 + threadIdx.x;  // 4096
    const int b = idx >> 9, c = idx & 511;
    float s = 0.f;
#pragma unroll
    for (int jc = 0; jc < 8; ++jc) s += part[((long)b * 8 + jc) * CDIM + c];
    ksum[idx] = s;
}

// z[b,i] = 1/(q[i,:].ksum[b,:] + 1e-6)
__global__ __launch_bounds__(256)
void k_z(const bf16* __restrict__ qb, const float* __restrict__ ksum, float* __restrict__ z)
{
    const long row = (long)blockIdx.x * 4 + (threadIdx.x >> 6);
    const int lane = threadIdx.x & 63;
    const int b = (int)(row >> 12);
    bh8 q = *(const bh8*)(qb + row * CDIM + lane * 8);
    const float* ks = ksum + (long)b * CDIM + lane * 8;
    f32x4 k0 = *(const f32x4*)ks, k1 = *(const f32x4*)(ks + 4);
    float s = 0.f;
#pragma unroll
    for (int j = 0; j < 4; ++j) { s += bf2f(q[j]) * k0[j]; s += bf2f(q[j + 4]) * k1[j]; }
    s = wsum(s);
    if (lane == 0) z[row] = 1.0f / (s + 1e-6f);
}

// LN over 512 (lnm), fp32 in -> bf16 out. 1 wave/row.
__global__ __launch_bounds__(256)
void k_ln512(const float* __restrict__ src, const float* __restrict__ g,
             const float* __restrict__ bta, bf16* __restrict__ dst)
{
    const long row = (long)blockIdx.x * 4 + (threadIdx.x >> 6);
    const int lane = threadIdx.x & 63;
    const float* p = src + row * CDIM + lane * 8;
    f32x4 a0 = *(const f32x4*)p, a1 = *(const f32x4*)(p + 4);
    float s = 0.f, ss = 0.f;
#pragma unroll
    for (int k = 0; k < 4; ++k) { s += a0[k] + a1[k]; ss += a0[k] * a0[k] + a1[k] * a1[k]; }
    s = wsum(s); ss = wsum(ss);
    const float mean = s * (1.0f / 512), var = ss * (1.0f / 512) - mean * mean;
    const float rstd = rsqrtf(var + 1e-5f);
    const float* gp = g + lane * 8;
    const float* bp = bta + lane * 8;
    f32x4 g0 = *(const f32x4*)gp, g1 = *(const f32x4*)(gp + 4);
    f32x4 b0 = *(const f32x4*)bp, b1 = *(const f32x4*)(bp + 4);
    bh8 o;
#pragma unroll
    for (int k = 0; k < 4; ++k) {
        o[k]     = f2bf((a0[k] - mean) * rstd * g0[k] + b0[k]);
        o[k + 4] = f2bf((a1[k] - mean) * rstd * g1[k] + b1[k]);
    }
    *(bh8*)(dst + row * CDIM + lane * 8) = o;
}

// depthwise 3x3 (SAME) + skip + LN(2048) + exact GELU. 1 block per token.
__global__ __launch_bounds__(256)
void k_dwlngelu(const bf16* __restrict__ a, const float* __restrict__ dww,
                const float* __restrict__ dwb, const float* __restrict__ g1,
                const float* __restrict__ b1, bf16* __restrict__ ax)
{
    const int bs = blockIdx.x;
    const int s = bs & 4095;
    const int h = s >> 6, w = s & 63;
    const int ch = threadIdx.x * 8;
    float wgt[8][9];
    const float* wp = dww + (long)ch * 9;
#pragma unroll
    for (int j = 0; j < 8; ++j)
#pragma unroll
        for (int kk = 0; kk < 9; ++kk) wgt[j][kk] = wp[j * 9 + kk];
    float acc[8], ctr[8];
#pragma unroll
    for (int j = 0; j < 8; ++j) acc[j] = dwb[ch + j];
#pragma unroll
    for (int dy = -1; dy <= 1; ++dy) {
        const int hh = h + dy;
        const bool vy = ((unsigned)hh < 64u);
#pragma unroll
        for (int dx = -1; dx <= 1; ++dx) {
            const int ww = w + dx;
            if (vy && ((unsigned)ww < 64u)) {
                const bf16* src = a + ((long)bs + dy * 64 + dx) * HIDD + ch;
                bh8 v = *(const bh8*)src;
                float f[8];
#pragma unroll
                for (int j = 0; j < 8; ++j) f[j] = bf2f(v[j]);
                const int kk = (dy + 1) * 3 + (dx + 1);
#pragma unroll
                for (int j = 0; j < 8; ++j) acc[j] += wgt[j][kk] * f[j];
                if (dy == 0 && dx == 0) {
#pragma unroll
                    for (int j = 0; j < 8; ++j) ctr[j] = f[j];
                }
            }
        }
    }
#pragma unroll
    for (int j = 0; j < 8; ++j) acc[j] += ctr[j];   // dw + a
    float s_ = 0.f, ss = 0.f;
#pragma unroll
    for (int j = 0; j < 8; ++j) { s_ += acc[j]; ss += acc[j] * acc[j]; }
    s_ = wsum(s_); ss = wsum(ss);
    __shared__ float red[8];
    const int wid = threadIdx.x >> 6, lane = threadIdx.x & 63;
    if (lane == 0) { red[wid] = s_; red[4 + wid] = ss; }
    __syncthreads();
    s_ = red[0] + red[1] + red[2] + red[3];
    ss = red[4] + red[5] + red[6] + red[7];
    const float mean = s_ * (1.0f / 2048), var = ss * (1.0f / 2048) - mean * mean;
    const float rstd = rsqrtf(var + 1e-5f);
    bh8 o;
#pragma unroll
    for (int j = 0; j < 8; ++j) {
        float y = (acc[j] - mean) * rstd * g1[ch + j] + b1[ch + j];
        float ge = 0.5f * y * (1.0f + erff(y * 0.70710678118654752f));
        o[j] = f2bf(ge);
    }
    *(bh8*)(ax + (long)bs * HIDD + ch) = o;
}

// ---------------------------------------------------------------- launch
extern "C" void kernel_launch(void* const* d_in, const int* in_sizes, int n_in,
                              void* d_out, int out_size, void* d_ws, size_t ws_size,
                              hipStream_t stream) {
    const float* x     = (const float*)d_in[0];
    const float* Wq    = (const float*)d_in[1];
    const float* bq    = (const float*)d_in[2];
    const float* Wk    = (const float*)d_in[3];
    const float* bk    = (const float*)d_in[4];
    const float* Wv    = (const float*)d_in[5];
    const float* bv    = (const float*)d_in[6];
    const float* scale = (const float*)d_in[7];
    const float* fc1_w = (const float*)d_in[8];
    const float* fc1_b = (const float*)d_in[9];
    const float* dw_w  = (const float*)d_in[10];
    const float* dw_b  = (const float*)d_in[11];
    const float* fc2_w = (const float*)d_in[12];
    const float* fc2_b = (const float*)d_in[13];
    const float* ln1_g = (const float*)d_in[14];
    const float* ln1_b = (const float*)d_in[15];
    const float* lnm_g = (const float*)d_in[16];
    const float* lnm_b = (const float*)d_in[17];
    float* out = (float*)d_out;
    char* p = (char*)d_ws;

    // ---- workspace layout (qraw/enhanced live in d_out itself) ----
    bf16*  xbT   = (bf16*)(p + 0);            // 32 MiB: x^T  -> later qb
    bf16*  kb    = (bf16*)(p + 33554432);     // 32 MiB: conv-k (bf16), softmax in-place
    bf16*  vb    = (bf16*)(p + 67108864);     // 32 MiB: conv-v
    bf16*  kvt   = (bf16*)(p + 100663296);    //  4 MiB: kv^T (B,512,512)
    bf16*  wqb   = (bf16*)(p + 104857600);
    bf16*  wkb   = (bf16*)(p + 105381888);
    bf16*  wvb   = (bf16*)(p + 105906176);
    bf16*  fc1wT = (bf16*)(p + 106430464);    //  2 MiB
    bf16*  fc2wT = (bf16*)(p + 108527616);    //  2 MiB
    float* invsc = (float*)(p + 110624768);
    float* qpart = (float*)(p + 110626816);
    float* qsum  = (float*)(p + 110757888);
    float* kpart = (float*)(p + 110774272);
    float* ksum  = (float*)(p + 110905344);
    float* zbuf  = (float*)(p + 110921728);
    const size_t REQUIRED = 111052800;
    // FFN-phase overlays (quarter = 2 batches = 8192 tokens):
    bf16*  qb    = xbT;                       // after convs, xbT dead
    bf16*  abuf  = (bf16*)(p + 0);            // after attn, qb dead (32 MiB)
    bf16*  axbuf = (bf16*)(p + 33554432);     // kb dead (32 MiB)
    bf16*  tbuf  = (bf16*)(p + 67108864);     // vb dead (8 MiB used)

    if (ws_size < REQUIRED) {   // sentinel encodes actual ws size in MiB
        k_fill<<<(out_size + 255) / 256, 256, 0, stream>>>(out, out_size, 100000.0f + (float)(ws_size >> 20));
        return;
    }

    const long NC = (long)NDIM * CDIM;  // 2,097,152 elements per batch

    // pack / convert params
    k_cvt_bf16<<<1024, 256, 0, stream>>>(Wq, wqb, 262144);
    k_cvt_bf16<<<1024, 256, 0, stream>>>(Wk, wkb, 262144);
    k_cvt_bf16<<<1024, 256, 0, stream>>>(Wv, wvb, 262144);
    k_transpose<<<dim3(32, 8, 1), 256, 0, stream>>>(fc1_w, fc1wT, 2048, 512, 0, 0);
    k_transpose<<<dim3(8, 32, 1), 256, 0, stream>>>(fc2_w, fc2wT, 512, 2048, 0, 0);
    k_invsc<<<1, 512, 0, stream>>>(scale, invsc);
    k_transpose<<<dim3(64, 8, BATCH), 256, 0, stream>>>(x, xbT, 4096, 512, NC, NC);

    // conv1x1 GEMMs: out[b](C=512, s=4096) = W @ x[b]; flat == raw (B,N,C) view
    gemm_bt<EP_F32_BROW><<<dim3(32, 4, 8), 256, 0, stream>>>(wqb, 512, 0, xbT, 512, NC, out, 4096, NC, 512, bq, nullptr, 0, nullptr, 0);
    gemm_bt<EP_BF16_BROW><<<dim3(32, 4, 8), 256, 0, stream>>>(wkb, 512, 0, xbT, 512, NC, kb, 4096, NC, 512, bk, nullptr, 0, nullptr, 0);
    gemm_bt<EP_BF16_BROW><<<dim3(32, 4, 8), 256, 0, stream>>>(wvb, 512, 0, xbT, 512, NC, vb, 4096, NC, 512, bv, nullptr, 0, nullptr, 0);

    // q/k nonlinear chains (qraw f32 lives in `out`)
    k_qcol_partial<<<dim3(2, 8, 8), 256, 0, stream>>>(out, qpart);
    k_qcol_reduce<<<16, 256, 0, stream>>>(qpart, qsum);
    k_qrow<<<8192, 256, 0, stream>>>(out, qsum, invsc, qb);
    k_krow<<<8192, 256, 0, stream>>>(kb, invsc);
    k_colsum_part<<<dim3(8, 8), 256, 0, stream>>>(kb, kpart);
    k_colsum_red<<<16, 256, 0, stream>>>(kpart, ksum);
    k_z<<<8192, 256, 0, stream>>>(qb, ksum, zbuf);

    // kv^T[b,d,c] = sum_j v[b,j,d] k[b,j,c]  (TN GEMM, K = 4096 rows)
    gemm_tn<<<dim3(4, 4, 8), 256, 0, stream>>>(vb, 512, NC, kb, 512, NC, kvt, 512, 262144, 4096);
    // enhanced = shortcut + z*(q@kv)  -> overwrites qraw in `out`
    gemm_bt<EP_ATTN><<<dim3(4, 32, 8), 256, 0, stream>>>(qb, 512, NC, kvt, 512, 262144, out, 512, NC, 512, nullptr, x, NC, zbuf, 4096);

    // MixFFN in 4 quarters (2 batches each) over dead attention buffers
    for (int q4 = 0; q4 < 4; ++q4) {
        float* outq = out + (long)q4 * 8192 * CDIM;
        k_ln512<<<2048, 256, 0, stream>>>(outq, lnm_g, lnm_b, tbuf);
        gemm_bt<EP_BF16_BCOL><<<dim3(16, 64, 1), 256, 0, stream>>>(tbuf, 512, 0, fc1wT, 512, 0, abuf, 2048, 0, 512, fc1_b, nullptr, 0, nullptr, 0);
        k_dwlngelu<<<8192, 256, 0, stream>>>(abuf, dw_w, dw_b, ln1_g, ln1_b, axbuf);
        gemm_bt<EP_OUT><<<dim3(4, 64, 1), 256, 0, stream>>>(axbuf, 2048, 0, fc2wT, 2048, 0, outq, 512, 0, 2048, fc2_b, outq, 0, nullptr, 0);
    }
}

// Round 3
// 835.673 us; speedup vs baseline: 1.4680x; 1.4680x over previous
//
#include <hip/hip_runtime.h>
#include <hip/hip_bf16.h>

typedef __hip_bfloat16 bf16;
typedef __attribute__((ext_vector_type(8))) short bh8;      // 8 x bf16 bits
typedef __attribute__((ext_vector_type(4))) float f32x4;

#define CDIM 512
#define NDIM 4096
#define HIDD 2048
#define BATCH 8

__device__ __forceinline__ float bf2f(short s) {
    union { unsigned u; float f; } c; c.u = ((unsigned)(unsigned short)s) << 16; return c.f;
}
__device__ __forceinline__ short f2bf(float f) {
    union { __hip_bfloat16 h; short s; } c; c.h = __float2bfloat16(f); return c.s;
}
__device__ __forceinline__ float wsum(float v) {
#pragma unroll
    for (int o = 32; o; o >>= 1) v += __shfl_xor(v, o);
    return v;
}
__device__ __forceinline__ float wmax(float v) {
#pragma unroll
    for (int o = 32; o; o >>= 1) v = fmaxf(v, __shfl_xor(v, o));
    return v;
}

#define GLL(g, l) __builtin_amdgcn_global_load_lds( \
    (const __attribute__((address_space(1))) unsigned int*)(g), \
    (__attribute__((address_space(3))) unsigned int*)(l), 16, 0, 0)

// ---------------------------------------------------------------- GEMM (NT)
// C[M,N] = A(M,K) @ Bt(N,K)^T, row-major bf16, fp32 accum. 128x128 tile, BK=64.
enum { EP_F32_BROW = 0, EP_BF16_BROW = 1, EP_ATTN = 3, EP_BF16_BCOL = 4, EP_OUT = 5 };

template<int MODE>
__global__ __launch_bounds__(256)
void gemm_bt(const bf16* __restrict__ A, int lda, long sA,
             const bf16* __restrict__ Bt, int ldb, long sB,
             void* __restrict__ Cp, int ldc, long sC, int K,
             const float* __restrict__ bias,
             const float* __restrict__ aux1, long sAux1,
             const float* __restrict__ aux2, long sAux2)
{
    __shared__ __align__(16) bf16 As[128 * 64];
    __shared__ __align__(16) bf16 Bs[128 * 64];
    const int bz = blockIdx.z;
    const bf16* Ab = A + (long)bz * sA + (long)blockIdx.y * 128 * lda;
    const bf16* Bb = Bt + (long)bz * sB + (long)blockIdx.x * 128 * ldb;
    const int t = threadIdx.x, lane = t & 63, wid = t >> 6;
    const int wm = wid >> 1, wn = wid & 1, lg = lane >> 4, lr = lane & 15;

    f32x4 acc[4][4];
#pragma unroll
    for (int m = 0; m < 4; ++m)
#pragma unroll
        for (int n = 0; n < 4; ++n) acc[m][n] = (f32x4){0.f, 0.f, 0.f, 0.f};

    for (int kt = 0; kt < K; kt += 64) {
#pragma unroll
        for (int i = 0; i < 4; ++i) {
            int ch = i * 256 + t;
            GLL(Ab + (long)(ch >> 3) * lda + kt + ((ch & 7) << 3), (char*)As + i * 4096 + wid * 1024);
            GLL(Bb + (long)(ch >> 3) * ldb + kt + ((ch & 7) << 3), (char*)Bs + i * 4096 + wid * 1024);
        }
        __syncthreads();
#pragma unroll
        for (int kk = 0; kk < 2; ++kk) {
            bh8 af[4], bfv[4];
#pragma unroll
            for (int m = 0; m < 4; ++m) af[m] = *(const bh8*)(As + (wm * 64 + m * 16 + lr) * 64 + kk * 32 + lg * 8);
#pragma unroll
            for (int n = 0; n < 4; ++n) bfv[n] = *(const bh8*)(Bs + (wn * 64 + n * 16 + lr) * 64 + kk * 32 + lg * 8);
#pragma unroll
            for (int m = 0; m < 4; ++m)
#pragma unroll
                for (int n = 0; n < 4; ++n)
                    acc[m][n] = __builtin_amdgcn_mfma_f32_16x16x32_bf16(af[m], bfv[n], acc[m][n], 0, 0, 0);
        }
        __syncthreads();
    }

    const int gr0 = blockIdx.y * 128 + wm * 64;
    const int gc0 = blockIdx.x * 128 + wn * 64;
#pragma unroll
    for (int m = 0; m < 4; ++m) {
#pragma unroll
        for (int n = 0; n < 4; ++n) {
            const int gc = gc0 + n * 16 + lr;
#pragma unroll
            for (int r = 0; r < 4; ++r) {
                const int gr = gr0 + m * 16 + lg * 4 + r;
                float v = acc[m][n][r];
                if constexpr (MODE == EP_F32_BROW) {
                    ((float*)Cp + (long)bz * sC)[(long)gr * ldc + gc] = v + bias[gr];
                } else if constexpr (MODE == EP_BF16_BROW) {
                    ((bf16*)Cp + (long)bz * sC)[(long)gr * ldc + gc] = __float2bfloat16(v + bias[gr]);
                } else if constexpr (MODE == EP_ATTN) {
                    const float* xg = aux1 + (long)bz * sAux1;   // x[b] (C, N): shortcut
                    const float* zg = aux2 + (long)bz * sAux2;   // z[b] (N)
                    ((float*)Cp + (long)bz * sC)[(long)gr * ldc + gc] = zg[gr] * v + xg[(long)gc * NDIM + gr];
                } else if constexpr (MODE == EP_BF16_BCOL) {
                    ((bf16*)Cp + (long)bz * sC)[(long)gr * ldc + gc] = __float2bfloat16(v + bias[gc]);
                } else { // EP_OUT: out = acc + bias[col] + out (in-place residual)
                    float* op = (float*)Cp;
                    const long idx = (long)gr * ldc + gc;
                    op[idx] = v + bias[gc] + aux1[idx];
                }
            }
        }
    }
}

// ---------------------------------------------------------------- GEMM (TN)
// C[m,n] = sum_k A[k,m]*B[k,n].  A:(K x M) row-major, B:(K x N) row-major.
__global__ __launch_bounds__(256)
void gemm_tn(const bf16* __restrict__ A, int lda, long sA,
             const bf16* __restrict__ B, int ldb, long sB,
             bf16* __restrict__ C, int ldc, long sC, int K)
{
    __shared__ __align__(16) short As[64 * 128];
    __shared__ __align__(16) short Bs[64 * 128];
    const int bz = blockIdx.z;
    const bf16* Ab = A + (long)bz * sA + blockIdx.y * 128;
    const bf16* Bb = B + (long)bz * sB + blockIdx.x * 128;
    const int t = threadIdx.x, lane = t & 63, wid = t >> 6;
    const int wm = wid >> 1, wn = wid & 1, lg = lane >> 4, lr = lane & 15;

    f32x4 acc[4][4];
#pragma unroll
    for (int m = 0; m < 4; ++m)
#pragma unroll
        for (int n = 0; n < 4; ++n) acc[m][n] = (f32x4){0.f, 0.f, 0.f, 0.f};

    for (int kt = 0; kt < K; kt += 64) {
#pragma unroll
        for (int i = 0; i < 4; ++i) {
            int ch = i * 256 + t;                       // tile elem16 index
            GLL(Ab + (long)(kt + (ch >> 4)) * lda + ((ch & 15) << 3), (char*)As + i * 4096 + wid * 1024);
            GLL(Bb + (long)(kt + (ch >> 4)) * ldb + ((ch & 15) << 3), (char*)Bs + i * 4096 + wid * 1024);
        }
        __syncthreads();
#pragma unroll
        for (int kk = 0; kk < 2; ++kk) {
            bh8 af[4], bfv[4];
#pragma unroll
            for (int m = 0; m < 4; ++m) {
                const int col = wm * 64 + m * 16 + lr;
#pragma unroll
                for (int u = 0; u < 8; ++u) af[m][u] = As[(kk * 32 + lg * 8 + u) * 128 + col];
            }
#pragma unroll
            for (int n = 0; n < 4; ++n) {
                const int col = wn * 64 + n * 16 + lr;
#pragma unroll
                for (int u = 0; u < 8; ++u) bfv[n][u] = Bs[(kk * 32 + lg * 8 + u) * 128 + col];
            }
#pragma unroll
            for (int m = 0; m < 4; ++m)
#pragma unroll
                for (int n = 0; n < 4; ++n)
                    acc[m][n] = __builtin_amdgcn_mfma_f32_16x16x32_bf16(af[m], bfv[n], acc[m][n], 0, 0, 0);
        }
        __syncthreads();
    }

    const int gr0 = blockIdx.y * 128 + wm * 64;
    const int gc0 = blockIdx.x * 128 + wn * 64;
#pragma unroll
    for (int m = 0; m < 4; ++m)
#pragma unroll
        for (int n = 0; n < 4; ++n) {
            const int gc = gc0 + n * 16 + lr;
#pragma unroll
            for (int r = 0; r < 4; ++r) {
                const int gr = gr0 + m * 16 + lg * 4 + r;
                (C + (long)bz * sC)[(long)gr * ldc + gc] = __float2bfloat16(acc[m][n][r]);
            }
        }
}

// ---------------------------------------------------------------- transpose
__global__ __launch_bounds__(256)
void k_transpose(const float* __restrict__ src, bf16* __restrict__ dst,
                 int Rd, int Cd, long sSrc, long sDst)
{
    __shared__ float tile[64][65];
    const float* s = src + (long)blockIdx.z * sSrc;
    bf16* d = dst + (long)blockIdx.z * sDst;
    const int r0 = blockIdx.x * 64, c0 = blockIdx.y * 64;
    const int t = threadIdx.x;
#pragma unroll 4
    for (int i = 0; i < 16; ++i) {
        int idx = i * 256 + t;
        int a = idx >> 6, b = idx & 63;
        tile[a][b] = s[(long)(c0 + a) * Rd + r0 + b];
    }
    __syncthreads();
#pragma unroll 4
    for (int i = 0; i < 16; ++i) {
        int idx = i * 256 + t;
        int a = idx >> 6, b = idx & 63;
        d[(long)(r0 + a) * Cd + c0 + b] = __float2bfloat16(tile[b][a]);
    }
}

__global__ void k_cvt_bf16(const float* __restrict__ in, bf16* __restrict__ out, int n) {
    int i = blockIdx.x * 256 + threadIdx.x;
    if (i < n) out[i] = __float2bfloat16(in[i]);
}

__global__ void k_invsc(const float* __restrict__ scale, float* __restrict__ invsc) {
    int j = threadIdx.x;
    invsc[j] = 1.0f / log1pf(expf(scale[j]));   // 1/softplus(scale)
}

__global__ void k_fill(float* o, int n, float v) {
    int i = blockIdx.x * 256 + threadIdx.x; if (i < n) o[i] = v;
}

// dw weights (2048,1,3,3) -> transposed [9][2048] f32
__global__ void k_dwT(const float* __restrict__ w, float* __restrict__ wT) {
    int i = blockIdx.x * 256 + threadIdx.x;
    if (i < HIDD * 9) {
        int chn = i / 9, kk = i % 9;
        wT[kk * HIDD + chn] = w[i];
    }
}

// ------------------------------------------------- q column-softmax denom
// softmax axis=1: column j of the (N,C) view = stride-CDIM walk of flat buf.
__global__ __launch_bounds__(256)
void k_qcol_partial(const float* __restrict__ qraw, float* __restrict__ qpart) {
    const int j = blockIdx.x * 256 + threadIdx.x;
    const int ic = blockIdx.y, b = blockIdx.z;     // 16 chunks of 256 rows
    const float* p = qraw + (long)b * (NDIM * CDIM) + (long)ic * 256 * CDIM + j;
    float s = 0.f;
    for (int i = 0; i < 256; ++i) s += expf(p[(long)i * CDIM]);
    qpart[((long)b * 16 + ic) * CDIM + j] = s;
}
__global__ __launch_bounds__(256)
void k_qcol_reduce(const float* __restrict__ qpart, float* __restrict__ qsum) {
    const int idx = blockIdx.x * 256 + threadIdx.x;  // B*C = 4096
    const int b = idx >> 9, j = idx & 511;
    float s = 0.f;
#pragma unroll
    for (int ic = 0; ic < 16; ++ic) s += qpart[((long)b * 16 + ic) * CDIM + j];
    qsum[idx] = s;
}

// q row pass: p=(exp/colsum + 1e-6)/sc, keep ||p||, cube, renorm -> bf16
__global__ __launch_bounds__(256)
void k_qrow(const float* __restrict__ qraw, const float* __restrict__ qsum,
            const float* __restrict__ invsc, bf16* __restrict__ qb)
{
    const long row = (long)blockIdx.x * 4 + (threadIdx.x >> 6);
    const int lane = threadIdx.x & 63;
    const int b = (int)(row >> 12);
    const float* p = qraw + row * CDIM + lane * 8;
    const float* qs = qsum + b * CDIM + lane * 8;
    const float* is = invsc + lane * 8;
    f32x4 v0 = *(const f32x4*)p, v1 = *(const f32x4*)(p + 4);
    f32x4 s0 = *(const f32x4*)qs, s1 = *(const f32x4*)(qs + 4);
    f32x4 i0 = *(const f32x4*)is, i1 = *(const f32x4*)(is + 4);
    float q[8];
#pragma unroll
    for (int k = 0; k < 4; ++k) {
        q[k]     = (expf(v0[k]) / s0[k] + 1e-6f) * i0[k];
        q[k + 4] = (expf(v1[k]) / s1[k] + 1e-6f) * i1[k];
    }
    float s2 = 0.f, s6 = 0.f, q3[8];
#pragma unroll
    for (int k = 0; k < 8; ++k) { s2 += q[k] * q[k]; float c = q[k] * q[k] * q[k]; q3[k] = c; s6 += c * c; }
    s2 = wsum(s2); s6 = wsum(s6);
    const float sc = sqrtf(s2) / sqrtf(s6);
    bh8 o;
#pragma unroll
    for (int k = 0; k < 8; ++k) o[k] = f2bf(q3[k] * sc);
    *(bh8*)(qb + row * CDIM + lane * 8) = o;
}

// k row pass (IN-PLACE, bf16): row softmax (axis=2), /sc, cube, renorm.
__global__ __launch_bounds__(256)
void k_krow(bf16* __restrict__ kb, const float* __restrict__ invsc)
{
    const long row = (long)blockIdx.x * 4 + (threadIdx.x >> 6);
    const int lane = threadIdx.x & 63;
    bh8 v = *(const bh8*)(kb + row * CDIM + lane * 8);
    const float* is = invsc + lane * 8;
    f32x4 i0 = *(const f32x4*)is, i1 = *(const f32x4*)(is + 4);
    float xv[8];
#pragma unroll
    for (int k = 0; k < 8; ++k) xv[k] = bf2f(v[k]);
    float mx = -1e30f;
#pragma unroll
    for (int k = 0; k < 8; ++k) mx = fmaxf(mx, xv[k]);
    mx = wmax(mx);
    float e[8], se = 0.f;
#pragma unroll
    for (int k = 0; k < 8; ++k) { e[k] = expf(xv[k] - mx); se += e[k]; }
    se = wsum(se);
    const float inv = 1.0f / se;
    float q[8];
#pragma unroll
    for (int k = 0; k < 4; ++k) {
        q[k]     = (e[k] * inv + 1e-6f) * i0[k];
        q[k + 4] = (e[k + 4] * inv + 1e-6f) * i1[k];
    }
    float s2 = 0.f, s6 = 0.f, q3[8];
#pragma unroll
    for (int k = 0; k < 8; ++k) { s2 += q[k] * q[k]; float c = q[k] * q[k] * q[k]; q3[k] = c; s6 += c * c; }
    s2 = wsum(s2); s6 = wsum(s6);
    const float sc = sqrtf(s2) / sqrtf(s6);
    bh8 o;
#pragma unroll
    for (int k = 0; k < 8; ++k) o[k] = f2bf(q3[k] * sc);
    *(bh8*)(kb + row * CDIM + lane * 8) = o;
}

// ksum[b,c] = sum_j kb[b,j,c] : two-stage column sum, 16 chunks of 256 rows.
__global__ __launch_bounds__(256)
void k_colsum_part(const bf16* __restrict__ kb, float* __restrict__ part) {
    const int b = blockIdx.y, jc = blockIdx.x, t = threadIdx.x;
    const bf16* p = kb + (long)b * (NDIM * CDIM) + (long)jc * 256 * CDIM + t * 2;
    float s0 = 0.f, s1 = 0.f;
    for (int j = 0; j < 256; ++j) {
        unsigned u = *(const unsigned*)(p + (long)j * CDIM);
        s0 += bf2f((short)(u & 0xffff));
        s1 += bf2f((short)(u >> 16));
    }
    float* o = part + ((long)b * 16 + jc) * CDIM + t * 2;
    o[0] = s0; o[1] = s1;
}
__global__ __launch_bounds__(256)
void k_colsum_red(const float* __restrict__ part, float* __restrict__ ksum) {
    const int idx = blockIdx.x * 256 + threadIdx.x;  // 4096
    const int b = idx >> 9, c = idx & 511;
    float s = 0.f;
#pragma unroll
    for (int jc = 0; jc < 16; ++jc) s += part[((long)b * 16 + jc) * CDIM + c];
    ksum[idx] = s;
}

// z[b,i] = 1/(q[i,:].ksum[b,:] + 1e-6)
__global__ __launch_bounds__(256)
void k_z(const bf16* __restrict__ qb, const float* __restrict__ ksum, float* __restrict__ z)
{
    const long row = (long)blockIdx.x * 4 + (threadIdx.x >> 6);
    const int lane = threadIdx.x & 63;
    const int b = (int)(row >> 12);
    bh8 q = *(const bh8*)(qb + row * CDIM + lane * 8);
    const float* ks = ksum + (long)b * CDIM + lane * 8;
    f32x4 k0 = *(const f32x4*)ks, k1 = *(const f32x4*)(ks + 4);
    float s = 0.f;
#pragma unroll
    for (int j = 0; j < 4; ++j) { s += bf2f(q[j]) * k0[j]; s += bf2f(q[j + 4]) * k1[j]; }
    s = wsum(s);
    if (lane == 0) z[row] = 1.0f / (s + 1e-6f);
}

// LN over 512 (lnm), fp32 in -> bf16 out. 1 wave/row.
__global__ __launch_bounds__(256)
void k_ln512(const float* __restrict__ src, const float* __restrict__ g,
             const float* __restrict__ bta, bf16* __restrict__ dst)
{
    const long row = (long)blockIdx.x * 4 + (threadIdx.x >> 6);
    const int lane = threadIdx.x & 63;
    const float* p = src + row * CDIM + lane * 8;
    f32x4 a0 = *(const f32x4*)p, a1 = *(const f32x4*)(p + 4);
    float s = 0.f, ss = 0.f;
#pragma unroll
    for (int k = 0; k < 4; ++k) { s += a0[k] + a1[k]; ss += a0[k] * a0[k] + a1[k] * a1[k]; }
    s = wsum(s); ss = wsum(ss);
    const float mean = s * (1.0f / 512), var = ss * (1.0f / 512) - mean * mean;
    const float rstd = rsqrtf(var + 1e-5f);
    const float* gp = g + lane * 8;
    const float* bp = bta + lane * 8;
    f32x4 g0 = *(const f32x4*)gp, g1 = *(const f32x4*)(gp + 4);
    f32x4 b0 = *(const f32x4*)bp, b1 = *(const f32x4*)(bp + 4);
    bh8 o;
#pragma unroll
    for (int k = 0; k < 4; ++k) {
        o[k]     = f2bf((a0[k] - mean) * rstd * g0[k] + b0[k]);
        o[k + 4] = f2bf((a1[k] - mean) * rstd * g1[k] + b1[k]);
    }
    *(bh8*)(dst + row * CDIM + lane * 8) = o;
}

// depthwise 3x3 (SAME) + skip + LN(2048) + exact GELU.
// 4 tokens (same row, 4-aligned) per block; coalesced transposed weights.
__global__ __launch_bounds__(256)
void k_dwlngelu4(const bf16* __restrict__ a, const float* __restrict__ dwwT,
                 const float* __restrict__ dwb, const float* __restrict__ g1,
                 const float* __restrict__ b1, bf16* __restrict__ ax)
{
    const long s0 = (long)blockIdx.x * 4;       // quad-base token (quarter-local)
    const int h = (int)((s0 >> 6) & 63);        // row within image (batch bdry is 64-aligned)
    const int w0 = (int)(s0 & 63);              // 4-aligned column
    const int ch = threadIdx.x * 8;

    float wgt[9][8];
#pragma unroll
    for (int kk = 0; kk < 9; ++kk) {
        f32x4 w0v = *(const f32x4*)(dwwT + kk * HIDD + ch);
        f32x4 w1v = *(const f32x4*)(dwwT + kk * HIDD + ch + 4);
#pragma unroll
        for (int j = 0; j < 4; ++j) { wgt[kk][j] = w0v[j]; wgt[kk][j + 4] = w1v[j]; }
    }
#pragma unroll
    for (int j = 0; j < 8; ++j) wgt[4][j] += 1.0f;   // fold the skip (dw + a)

    float acc[4][8];
    {
        f32x4 d0 = *(const f32x4*)(dwb + ch), d1 = *(const f32x4*)(dwb + ch + 4);
#pragma unroll
        for (int ti = 0; ti < 4; ++ti)
#pragma unroll
            for (int j = 0; j < 4; ++j) { acc[ti][j] = d0[j]; acc[ti][j + 4] = d1[j]; }
    }

#pragma unroll
    for (int dy = -1; dy <= 1; ++dy) {
        const int hh = h + dy;
        if ((unsigned)hh >= 64u) continue;       // wave-uniform
#pragma unroll
        for (int c = -1; c <= 4; ++c) {
            const int ww = w0 + c;
            if ((unsigned)ww >= 64u) continue;   // wave-uniform
            bh8 v = *(const bh8*)(a + (s0 + (long)dy * 64 + c) * HIDD + ch);
            float f[8];
#pragma unroll
            for (int j = 0; j < 8; ++j) f[j] = bf2f(v[j]);
#pragma unroll
            for (int ti = 0; ti < 4; ++ti) {
                const int dx = c - ti;
                if (dx < -1 || dx > 1) continue;
                const int kk = (dy + 1) * 3 + (dx + 1);
#pragma unroll
                for (int j = 0; j < 8; ++j) acc[ti][j] += wgt[kk][j] * f[j];
            }
        }
    }

    // LN(2048) per token
    float sv[4], qv[4];
#pragma unroll
    for (int ti = 0; ti < 4; ++ti) {
        float s = 0.f, q = 0.f;
#pragma unroll
        for (int j = 0; j < 8; ++j) { s += acc[ti][j]; q += acc[ti][j] * acc[ti][j]; }
        sv[ti] = wsum(s); qv[ti] = wsum(q);
    }
    __shared__ float red[4][4][2];
    const int wid = threadIdx.x >> 6, lane = threadIdx.x & 63;
    if (lane == 0)
#pragma unroll
        for (int ti = 0; ti < 4; ++ti) { red[wid][ti][0] = sv[ti]; red[wid][ti][1] = qv[ti]; }
    __syncthreads();

    f32x4 ga = *(const f32x4*)(g1 + ch), gb = *(const f32x4*)(g1 + ch + 4);
    f32x4 ba = *(const f32x4*)(b1 + ch), bb = *(const f32x4*)(b1 + ch + 4);
    float gg[8], bb8[8];
#pragma unroll
    for (int j = 0; j < 4; ++j) { gg[j] = ga[j]; gg[j + 4] = gb[j]; bb8[j] = ba[j]; bb8[j + 4] = bb[j]; }

#pragma unroll
    for (int ti = 0; ti < 4; ++ti) {
        const float s = red[0][ti][0] + red[1][ti][0] + red[2][ti][0] + red[3][ti][0];
        const float q = red[0][ti][1] + red[1][ti][1] + red[2][ti][1] + red[3][ti][1];
        const float mean = s * (1.0f / 2048), var = q * (1.0f / 2048) - mean * mean;
        const float rstd = rsqrtf(var + 1e-5f);
        bh8 o;
#pragma unroll
        for (int j = 0; j < 8; ++j) {
            float y = (acc[ti][j] - mean) * rstd * gg[j] + bb8[j];
            o[j] = f2bf(0.5f * y * (1.0f + erff(y * 0.70710678118654752f)));
        }
        *(bh8*)(ax + (s0 + ti) * HIDD + ch) = o;
    }
}

// ---------------------------------------------------------------- launch
extern "C" void kernel_launch(void* const* d_in, const int* in_sizes, int n_in,
                              void* d_out, int out_size, void* d_ws, size_t ws_size,
                              hipStream_t stream) {
    const float* x     = (const float*)d_in[0];
    const float* Wq    = (const float*)d_in[1];
    const float* bq    = (const float*)d_in[2];
    const float* Wk    = (const float*)d_in[3];
    const float* bk    = (const float*)d_in[4];
    const float* Wv    = (const float*)d_in[5];
    const float* bv    = (const float*)d_in[6];
    const float* scale = (const float*)d_in[7];
    const float* fc1_w = (const float*)d_in[8];
    const float* fc1_b = (const float*)d_in[9];
    const float* dw_w  = (const float*)d_in[10];
    const float* dw_b  = (const float*)d_in[11];
    const float* fc2_w = (const float*)d_in[12];
    const float* fc2_b = (const float*)d_in[13];
    const float* ln1_g = (const float*)d_in[14];
    const float* ln1_b = (const float*)d_in[15];
    const float* lnm_g = (const float*)d_in[16];
    const float* lnm_b = (const float*)d_in[17];
    float* out = (float*)d_out;
    char* p = (char*)d_ws;

    // ---- workspace layout (qraw/enhanced live in d_out itself) ----
    bf16*  xbT   = (bf16*)(p + 0);            // 32 MiB: x^T  -> later qb
    bf16*  kb    = (bf16*)(p + 33554432);     // 32 MiB: conv-k (bf16), softmax in-place
    bf16*  vb    = (bf16*)(p + 67108864);     // 32 MiB: conv-v
    bf16*  kvt   = (bf16*)(p + 100663296);    //  4 MiB: kv^T (B,512,512)
    bf16*  wqb   = (bf16*)(p + 104857600);
    bf16*  wkb   = (bf16*)(p + 105381888);
    bf16*  wvb   = (bf16*)(p + 105906176);
    bf16*  fc1wT = (bf16*)(p + 106430464);    //  2 MiB
    bf16*  fc2wT = (bf16*)(p + 108527616);    //  2 MiB
    float* invsc = (float*)(p + 110624768);
    float* dwwT  = (float*)(p + 110626816);   // 73,728 B (written pre-FFN; old qpart slot)
    float* qsum  = (float*)(p + 110757888);
    float* kpartX= (float*)(p + 110774272);   // (unused; kept for layout clarity)
    float* ksum  = (float*)(p + 110905344);
    float* zbuf  = (float*)(p + 110921728);
    const size_t REQUIRED = 111052800;
    // overlays: qpart/kpart live in the kvt region (dead until kv GEMM)
    float* qpart = (float*)kvt;               // 8*16*512*4 = 262,144 B
    float* kpart = (float*)((char*)kvt + 262144);   // 262,144 B
    // FFN-phase overlays (quarter = 2 batches = 8192 tokens):
    bf16*  qb    = xbT;                       // after convs, xbT dead
    bf16*  abuf  = (bf16*)(p + 0);            // after attn, qb dead (32 MiB)
    bf16*  axbuf = (bf16*)(p + 33554432);     // kb dead (32 MiB)
    bf16*  tbuf  = (bf16*)(p + 67108864);     // vb dead (8 MiB used)

    if (ws_size < REQUIRED) {   // sentinel encodes actual ws size in MiB
        k_fill<<<(out_size + 255) / 256, 256, 0, stream>>>(out, out_size, 100000.0f + (float)(ws_size >> 20));
        return;
    }
    (void)kpartX;

    const long NC = (long)NDIM * CDIM;  // 2,097,152 elements per batch

    // pack / convert params
    k_cvt_bf16<<<1024, 256, 0, stream>>>(Wq, wqb, 262144);
    k_cvt_bf16<<<1024, 256, 0, stream>>>(Wk, wkb, 262144);
    k_cvt_bf16<<<1024, 256, 0, stream>>>(Wv, wvb, 262144);
    k_transpose<<<dim3(32, 8, 1), 256, 0, stream>>>(fc1_w, fc1wT, 2048, 512, 0, 0);
    k_transpose<<<dim3(8, 32, 1), 256, 0, stream>>>(fc2_w, fc2wT, 512, 2048, 0, 0);
    k_invsc<<<1, 512, 0, stream>>>(scale, invsc);
    k_transpose<<<dim3(64, 8, BATCH), 256, 0, stream>>>(x, xbT, 4096, 512, NC, NC);

    // conv1x1 GEMMs: out[b](C=512, s=4096) = W @ x[b]; flat == raw (B,N,C) view
    gemm_bt<EP_F32_BROW><<<dim3(32, 4, 8), 256, 0, stream>>>(wqb, 512, 0, xbT, 512, NC, out, 4096, NC, 512, bq, nullptr, 0, nullptr, 0);
    gemm_bt<EP_BF16_BROW><<<dim3(32, 4, 8), 256, 0, stream>>>(wkb, 512, 0, xbT, 512, NC, kb, 4096, NC, 512, bk, nullptr, 0, nullptr, 0);
    gemm_bt<EP_BF16_BROW><<<dim3(32, 4, 8), 256, 0, stream>>>(wvb, 512, 0, xbT, 512, NC, vb, 4096, NC, 512, bv, nullptr, 0, nullptr, 0);

    // q/k nonlinear chains (qraw f32 lives in `out`)
    k_qcol_partial<<<dim3(2, 16, 8), 256, 0, stream>>>(out, qpart);
    k_qcol_reduce<<<16, 256, 0, stream>>>(qpart, qsum);
    k_qrow<<<8192, 256, 0, stream>>>(out, qsum, invsc, qb);
    k_krow<<<8192, 256, 0, stream>>>(kb, invsc);
    k_colsum_part<<<dim3(16, 8), 256, 0, stream>>>(kb, kpart);
    k_colsum_red<<<16, 256, 0, stream>>>(kpart, ksum);
    k_z<<<8192, 256, 0, stream>>>(qb, ksum, zbuf);

    // kv^T[b,d,c] = sum_j v[b,j,d] k[b,j,c]  (TN GEMM, K = 4096 rows)
    gemm_tn<<<dim3(4, 4, 8), 256, 0, stream>>>(vb, 512, NC, kb, 512, NC, kvt, 512, 262144, 4096);
    // enhanced = shortcut + z*(q@kv)  -> overwrites qraw in `out`
    gemm_bt<EP_ATTN><<<dim3(4, 32, 8), 256, 0, stream>>>(qb, 512, NC, kvt, 512, 262144, out, 512, NC, 512, nullptr, x, NC, zbuf, 4096);

    // MixFFN in 4 quarters (2 batches each) over dead attention buffers
    k_dwT<<<72, 256, 0, stream>>>(dw_w, dwwT);
    for (int q4 = 0; q4 < 4; ++q4) {
        float* outq = out + (long)q4 * 8192 * CDIM;
        k_ln512<<<2048, 256, 0, stream>>>(outq, lnm_g, lnm_b, tbuf);
        gemm_bt<EP_BF16_BCOL><<<dim3(16, 64, 1), 256, 0, stream>>>(tbuf, 512, 0, fc1wT, 512, 0, abuf, 2048, 0, 512, fc1_b, nullptr, 0, nullptr, 0);
        k_dwlngelu4<<<2048, 256, 0, stream>>>(abuf, dwwT, dw_b, ln1_g, ln1_b, axbuf);
        gemm_bt<EP_OUT><<<dim3(4, 64, 1), 256, 0, stream>>>(axbuf, 2048, 0, fc2wT, 2048, 0, outq, 512, 0, 2048, fc2_b, outq, 0, nullptr, 0);
    }
}

// Round 4
// 776.362 us; speedup vs baseline: 1.5801x; 1.0764x over previous
//
#include <hip/hip_runtime.h>
#include <hip/hip_bf16.h>

typedef __hip_bfloat16 bf16;
typedef __attribute__((ext_vector_type(8))) short bh8;      // 8 x bf16 bits
typedef __attribute__((ext_vector_type(4))) short bh4;      // 4 x bf16 bits
typedef __attribute__((ext_vector_type(4))) float f32x4;

#define CDIM 512
#define NDIM 4096
#define HIDD 2048
#define BATCH 8

__device__ __forceinline__ float bf2f(short s) {
    union { unsigned u; float f; } c; c.u = ((unsigned)(unsigned short)s) << 16; return c.f;
}
__device__ __forceinline__ short f2bf(float f) {
    union { __hip_bfloat16 h; short s; } c; c.h = __float2bfloat16(f); return c.s;
}
__device__ __forceinline__ float wsum(float v) {
#pragma unroll
    for (int o = 32; o; o >>= 1) v += __shfl_xor(v, o);
    return v;
}
__device__ __forceinline__ float wmax(float v) {
#pragma unroll
    for (int o = 32; o; o >>= 1) v = fmaxf(v, __shfl_xor(v, o));
    return v;
}

#define GLL(g, l) __builtin_amdgcn_global_load_lds( \
    (const __attribute__((address_space(1))) unsigned int*)(g), \
    (__attribute__((address_space(3))) unsigned int*)(l), 16, 0, 0)

// ---------------------------------------------------------------- GEMM (NT)
// C[M,N] = A(M,K) @ Bt(N,K)^T, row-major bf16, fp32 accum. 128x128 tile, BK=64.
enum { EP_F32_BROW = 0, EP_BF16_BROW = 1, EP_ATTN = 3, EP_BF16_BCOL = 4, EP_OUT = 5 };

template<int MODE>
__global__ __launch_bounds__(256)
void gemm_bt(const bf16* __restrict__ A, int lda, long sA,
             const bf16* __restrict__ Bt, int ldb, long sB,
             void* __restrict__ Cp, int ldc, long sC, int K,
             const float* __restrict__ bias,
             const float* __restrict__ aux1, long sAux1,
             const float* __restrict__ aux2, long sAux2)
{
    __shared__ __align__(16) bf16 As[128 * 64];
    __shared__ __align__(16) bf16 Bs[128 * 64];
    const int bz = blockIdx.z;
    const bf16* Ab = A + (long)bz * sA + (long)blockIdx.y * 128 * lda;
    const bf16* Bb = Bt + (long)bz * sB + (long)blockIdx.x * 128 * ldb;
    const int t = threadIdx.x, lane = t & 63, wid = t >> 6;
    const int wm = wid >> 1, wn = wid & 1, lg = lane >> 4, lr = lane & 15;

    f32x4 acc[4][4];
#pragma unroll
    for (int m = 0; m < 4; ++m)
#pragma unroll
        for (int n = 0; n < 4; ++n) acc[m][n] = (f32x4){0.f, 0.f, 0.f, 0.f};

    for (int kt = 0; kt < K; kt += 64) {
#pragma unroll
        for (int i = 0; i < 4; ++i) {
            int ch = i * 256 + t;
            GLL(Ab + (long)(ch >> 3) * lda + kt + ((ch & 7) << 3), (char*)As + i * 4096 + wid * 1024);
            GLL(Bb + (long)(ch >> 3) * ldb + kt + ((ch & 7) << 3), (char*)Bs + i * 4096 + wid * 1024);
        }
        __syncthreads();
#pragma unroll
        for (int kk = 0; kk < 2; ++kk) {
            bh8 af[4], bfv[4];
#pragma unroll
            for (int m = 0; m < 4; ++m) af[m] = *(const bh8*)(As + (wm * 64 + m * 16 + lr) * 64 + kk * 32 + lg * 8);
#pragma unroll
            for (int n = 0; n < 4; ++n) bfv[n] = *(const bh8*)(Bs + (wn * 64 + n * 16 + lr) * 64 + kk * 32 + lg * 8);
#pragma unroll
            for (int m = 0; m < 4; ++m)
#pragma unroll
                for (int n = 0; n < 4; ++n)
                    acc[m][n] = __builtin_amdgcn_mfma_f32_16x16x32_bf16(af[m], bfv[n], acc[m][n], 0, 0, 0);
        }
        __syncthreads();
    }

    const int gr0 = blockIdx.y * 128 + wm * 64;
    const int gc0 = blockIdx.x * 128 + wn * 64;
#pragma unroll
    for (int m = 0; m < 4; ++m) {
#pragma unroll
        for (int n = 0; n < 4; ++n) {
            const int gc = gc0 + n * 16 + lr;
#pragma unroll
            for (int r = 0; r < 4; ++r) {
                const int gr = gr0 + m * 16 + lg * 4 + r;
                float v = acc[m][n][r];
                if constexpr (MODE == EP_F32_BROW) {
                    ((float*)Cp + (long)bz * sC)[(long)gr * ldc + gc] = v + bias[gr];
                } else if constexpr (MODE == EP_BF16_BROW) {
                    ((bf16*)Cp + (long)bz * sC)[(long)gr * ldc + gc] = __float2bfloat16(v + bias[gr]);
                } else if constexpr (MODE == EP_ATTN) {
                    const float* xg = aux1 + (long)bz * sAux1;   // x[b] (C, N): shortcut
                    const float* zg = aux2 + (long)bz * sAux2;   // z[b] (N)
                    ((float*)Cp + (long)bz * sC)[(long)gr * ldc + gc] = zg[gr] * v + xg[(long)gc * NDIM + gr];
                } else if constexpr (MODE == EP_BF16_BCOL) {
                    ((bf16*)Cp + (long)bz * sC)[(long)gr * ldc + gc] = __float2bfloat16(v + bias[gc]);
                } else { // EP_OUT: out = acc + bias[col] + out (in-place residual)
                    float* op = (float*)Cp;
                    const long idx = (long)gr * ldc + gc;
                    op[idx] = v + bias[gc] + aux1[idx];
                }
            }
        }
    }
}

// ---------------------------------------------------------------- GEMM (TN, split-K)
// part[b,ks] (512x512) = A[b,ks-chunk]^T @ B[b,ks-chunk];  A,B: (4096 x 512) row-major.
// Grid (4, 4, 8*8): z = b*8 + ks, each handles K-chunk of 512.
// LDS tiles use XOR-swizzled staging (source-side) so the column-fragment
// reads are bank-conflict-free (4 lane-groups -> 4 disjoint bank quads).
__global__ __launch_bounds__(256)
void gemm_tn_splitk(const bf16* __restrict__ A, int lda, long sA,
                    const bf16* __restrict__ B, int ldb, long sB,
                    float* __restrict__ part)
{
    __shared__ __align__(16) short As[64 * 128];
    __shared__ __align__(16) short Bs[64 * 128];
    const int bz = blockIdx.z >> 3, ks = blockIdx.z & 7;
    const bf16* Ab = A + (long)bz * sA + (long)ks * 512 * lda + blockIdx.y * 128;
    const bf16* Bb = B + (long)bz * sB + (long)ks * 512 * ldb + blockIdx.x * 128;
    const int t = threadIdx.x, lane = t & 63, wid = t >> 6;
    const int wm = wid >> 1, wn = wid & 1, lg = lane >> 4, lr = lane & 15;

    f32x4 acc[4][4];
#pragma unroll
    for (int m = 0; m < 4; ++m)
#pragma unroll
        for (int n = 0; n < 4; ++n) acc[m][n] = (f32x4){0.f, 0.f, 0.f, 0.f};

    for (int kt = 0; kt < 512; kt += 64) {
#pragma unroll
        for (int i = 0; i < 4; ++i) {
            const int ch = i * 256 + t;                 // linear 16B-chunk id
            const int row = ch >> 4;                    // k within tile
            const int cs = (ch & 15) ^ (((row >> 3) & 3) << 1);  // swizzled src chunk
            GLL(Ab + (long)(kt + row) * lda + (cs << 3), (char*)As + i * 4096 + wid * 1024);
            GLL(Bb + (long)(kt + row) * ldb + (cs << 3), (char*)Bs + i * 4096 + wid * 1024);
        }
        __syncthreads();
#pragma unroll
        for (int kk = 0; kk < 2; ++kk) {
            bh8 af[4], bfv[4];
#pragma unroll
            for (int m = 0; m < 4; ++m) {
                const int col = wm * 64 + m * 16 + lr;
#pragma unroll
                for (int u = 0; u < 8; ++u) {
                    const int row = kk * 32 + lg * 8 + u;
                    af[m][u] = As[row * 128 + (((col >> 3) ^ (((row >> 3) & 3) << 1)) << 3) + (col & 7)];
                }
            }
#pragma unroll
            for (int n = 0; n < 4; ++n) {
                const int col = wn * 64 + n * 16 + lr;
#pragma unroll
                for (int u = 0; u < 8; ++u) {
                    const int row = kk * 32 + lg * 8 + u;
                    bfv[n][u] = Bs[row * 128 + (((col >> 3) ^ (((row >> 3) & 3) << 1)) << 3) + (col & 7)];
                }
            }
#pragma unroll
            for (int m = 0; m < 4; ++m)
#pragma unroll
                for (int n = 0; n < 4; ++n)
                    acc[m][n] = __builtin_amdgcn_mfma_f32_16x16x32_bf16(af[m], bfv[n], acc[m][n], 0, 0, 0);
        }
        __syncthreads();
    }

    float* po = part + ((long)blockIdx.z << 18);        // 512*512 per (b,ks)
    const int gr0 = blockIdx.y * 128 + wm * 64;
    const int gc0 = blockIdx.x * 128 + wn * 64;
#pragma unroll
    for (int m = 0; m < 4; ++m)
#pragma unroll
        for (int n = 0; n < 4; ++n) {
            const int gc = gc0 + n * 16 + lr;
#pragma unroll
            for (int r = 0; r < 4; ++r) {
                const int gr = gr0 + m * 16 + lg * 4 + r;
                po[(long)gr * 512 + gc] = acc[m][n][r];
            }
        }
}

// kvt[b] = bf16( sum_ks part[b,ks] )   — 4 elems/thread, vectorized.
__global__ __launch_bounds__(256)
void k_kvred(const float* __restrict__ part, bf16* __restrict__ kvt)
{
    const long e = ((long)blockIdx.x * 256 + threadIdx.x) * 4;
    const int b = (int)(e >> 18);
    const int off = (int)(e & 262143);
    f32x4 s = (f32x4){0.f, 0.f, 0.f, 0.f};
#pragma unroll
    for (int ks = 0; ks < 8; ++ks) {
        f32x4 v = *(const f32x4*)(part + (((long)(b * 8 + ks)) << 18) + off);
        s = s + v;
    }
    bh4 o;
#pragma unroll
    for (int j = 0; j < 4; ++j) o[j] = f2bf(s[j]);
    *(bh4*)(kvt + ((long)b << 18) + off) = o;
}

// ---------------------------------------------------------------- transpose
__global__ __launch_bounds__(256)
void k_transpose(const float* __restrict__ src, bf16* __restrict__ dst,
                 int Rd, int Cd, long sSrc, long sDst)
{
    __shared__ float tile[64][65];
    const float* s = src + (long)blockIdx.z * sSrc;
    bf16* d = dst + (long)blockIdx.z * sDst;
    const int r0 = blockIdx.x * 64, c0 = blockIdx.y * 64;
    const int t = threadIdx.x;
#pragma unroll 4
    for (int i = 0; i < 16; ++i) {
        int idx = i * 256 + t;
        int a = idx >> 6, b = idx & 63;
        tile[a][b] = s[(long)(c0 + a) * Rd + r0 + b];
    }
    __syncthreads();
#pragma unroll 4
    for (int i = 0; i < 16; ++i) {
        int idx = i * 256 + t;
        int a = idx >> 6, b = idx & 63;
        d[(long)(r0 + a) * Cd + c0 + b] = __float2bfloat16(tile[b][a]);
    }
}

__global__ void k_cvt_bf16(const float* __restrict__ in, bf16* __restrict__ out, int n) {
    int i = blockIdx.x * 256 + threadIdx.x;
    if (i < n) out[i] = __float2bfloat16(in[i]);
}

__global__ void k_invsc(const float* __restrict__ scale, float* __restrict__ invsc) {
    int j = threadIdx.x;
    invsc[j] = 1.0f / log1pf(expf(scale[j]));   // 1/softplus(scale)
}

__global__ void k_fill(float* o, int n, float v) {
    int i = blockIdx.x * 256 + threadIdx.x; if (i < n) o[i] = v;
}

// dw weights (2048,1,3,3) -> transposed [9][2048] f32
__global__ void k_dwT(const float* __restrict__ w, float* __restrict__ wT) {
    int i = blockIdx.x * 256 + threadIdx.x;
    if (i < HIDD * 9) {
        int chn = i / 9, kk = i % 9;
        wT[kk * HIDD + chn] = w[i];
    }
}

// ------------------------------------------------- q column-softmax denom
__global__ __launch_bounds__(256)
void k_qcol_partial(const float* __restrict__ qraw, float* __restrict__ qpart) {
    const int j = blockIdx.x * 256 + threadIdx.x;
    const int ic = blockIdx.y, b = blockIdx.z;     // 16 chunks of 256 rows
    const float* p = qraw + (long)b * (NDIM * CDIM) + (long)ic * 256 * CDIM + j;
    float s = 0.f;
    for (int i = 0; i < 256; ++i) s += expf(p[(long)i * CDIM]);
    qpart[((long)b * 16 + ic) * CDIM + j] = s;
}
__global__ __launch_bounds__(256)
void k_qcol_reduce(const float* __restrict__ qpart, float* __restrict__ qsum) {
    const int idx = blockIdx.x * 256 + threadIdx.x;  // B*C = 4096
    const int b = idx >> 9, j = idx & 511;
    float s = 0.f;
#pragma unroll
    for (int ic = 0; ic < 16; ++ic) s += qpart[((long)b * 16 + ic) * CDIM + j];
    qsum[idx] = s;
}

// q row pass: p=(exp/colsum + 1e-6)/sc, keep ||p||, cube, renorm -> bf16
__global__ __launch_bounds__(256)
void k_qrow(const float* __restrict__ qraw, const float* __restrict__ qsum,
            const float* __restrict__ invsc, bf16* __restrict__ qb)
{
    const long row = (long)blockIdx.x * 4 + (threadIdx.x >> 6);
    const int lane = threadIdx.x & 63;
    const int b = (int)(row >> 12);
    const float* p = qraw + row * CDIM + lane * 8;
    const float* qs = qsum + b * CDIM + lane * 8;
    const float* is = invsc + lane * 8;
    f32x4 v0 = *(const f32x4*)p, v1 = *(const f32x4*)(p + 4);
    f32x4 s0 = *(const f32x4*)qs, s1 = *(const f32x4*)(qs + 4);
    f32x4 i0 = *(const f32x4*)is, i1 = *(const f32x4*)(is + 4);
    float q[8];
#pragma unroll
    for (int k = 0; k < 4; ++k) {
        q[k]     = (expf(v0[k]) / s0[k] + 1e-6f) * i0[k];
        q[k + 4] = (expf(v1[k]) / s1[k] + 1e-6f) * i1[k];
    }
    float s2 = 0.f, s6 = 0.f, q3[8];
#pragma unroll
    for (int k = 0; k < 8; ++k) { s2 += q[k] * q[k]; float c = q[k] * q[k] * q[k]; q3[k] = c; s6 += c * c; }
    s2 = wsum(s2); s6 = wsum(s6);
    const float sc = sqrtf(s2) / sqrtf(s6);
    bh8 o;
#pragma unroll
    for (int k = 0; k < 8; ++k) o[k] = f2bf(q3[k] * sc);
    *(bh8*)(qb + row * CDIM + lane * 8) = o;
}

// k row pass (IN-PLACE, bf16): row softmax (axis=2), /sc, cube, renorm.
__global__ __launch_bounds__(256)
void k_krow(bf16* __restrict__ kb, const float* __restrict__ invsc)
{
    const long row = (long)blockIdx.x * 4 + (threadIdx.x >> 6);
    const int lane = threadIdx.x & 63;
    bh8 v = *(const bh8*)(kb + row * CDIM + lane * 8);
    const float* is = invsc + lane * 8;
    f32x4 i0 = *(const f32x4*)is, i1 = *(const f32x4*)(is + 4);
    float xv[8];
#pragma unroll
    for (int k = 0; k < 8; ++k) xv[k] = bf2f(v[k]);
    float mx = -1e30f;
#pragma unroll
    for (int k = 0; k < 8; ++k) mx = fmaxf(mx, xv[k]);
    mx = wmax(mx);
    float e[8], se = 0.f;
#pragma unroll
    for (int k = 0; k < 8; ++k) { e[k] = expf(xv[k] - mx); se += e[k]; }
    se = wsum(se);
    const float inv = 1.0f / se;
    float q[8];
#pragma unroll
    for (int k = 0; k < 4; ++k) {
        q[k]     = (e[k] * inv + 1e-6f) * i0[k];
        q[k + 4] = (e[k + 4] * inv + 1e-6f) * i1[k];
    }
    float s2 = 0.f, s6 = 0.f, q3[8];
#pragma unroll
    for (int k = 0; k < 8; ++k) { s2 += q[k] * q[k]; float c = q[k] * q[k] * q[k]; q3[k] = c; s6 += c * c; }
    s2 = wsum(s2); s6 = wsum(s6);
    const float sc = sqrtf(s2) / sqrtf(s6);
    bh8 o;
#pragma unroll
    for (int k = 0; k < 8; ++k) o[k] = f2bf(q3[k] * sc);
    *(bh8*)(kb + row * CDIM + lane * 8) = o;
}

// ksum[b,c] = sum_j kb[b,j,c] : two-stage column sum, 16 chunks of 256 rows.
__global__ __launch_bounds__(256)
void k_colsum_part(const bf16* __restrict__ kb, float* __restrict__ part) {
    const int b = blockIdx.y, jc = blockIdx.x, t = threadIdx.x;
    const bf16* p = kb + (long)b * (NDIM * CDIM) + (long)jc * 256 * CDIM + t * 2;
    float s0 = 0.f, s1 = 0.f;
    for (int j = 0; j < 256; ++j) {
        unsigned u = *(const unsigned*)(p + (long)j * CDIM);
        s0 += bf2f((short)(u & 0xffff));
        s1 += bf2f((short)(u >> 16));
    }
    float* o = part + ((long)b * 16 + jc) * CDIM + t * 2;
    o[0] = s0; o[1] = s1;
}
__global__ __launch_bounds__(256)
void k_colsum_red(const float* __restrict__ part, float* __restrict__ ksum) {
    const int idx = blockIdx.x * 256 + threadIdx.x;  // 4096
    const int b = idx >> 9, c = idx & 511;
    float s = 0.f;
#pragma unroll
    for (int jc = 0; jc < 16; ++jc) s += part[((long)b * 16 + jc) * CDIM + c];
    ksum[idx] = s;
}

// z[b,i] = 1/(q[i,:].ksum[b,:] + 1e-6)
__global__ __launch_bounds__(256)
void k_z(const bf16* __restrict__ qb, const float* __restrict__ ksum, float* __restrict__ z)
{
    const long row = (long)blockIdx.x * 4 + (threadIdx.x >> 6);
    const int lane = threadIdx.x & 63;
    const int b = (int)(row >> 12);
    bh8 q = *(const bh8*)(qb + row * CDIM + lane * 8);
    const float* ks = ksum + (long)b * CDIM + lane * 8;
    f32x4 k0 = *(const f32x4*)ks, k1 = *(const f32x4*)(ks + 4);
    float s = 0.f;
#pragma unroll
    for (int j = 0; j < 4; ++j) { s += bf2f(q[j]) * k0[j]; s += bf2f(q[j + 4]) * k1[j]; }
    s = wsum(s);
    if (lane == 0) z[row] = 1.0f / (s + 1e-6f);
}

// LN over 512 (lnm), fp32 in -> bf16 out. 1 wave/row.
__global__ __launch_bounds__(256)
void k_ln512(const float* __restrict__ src, const float* __restrict__ g,
             const float* __restrict__ bta, bf16* __restrict__ dst)
{
    const long row = (long)blockIdx.x * 4 + (threadIdx.x >> 6);
    const int lane = threadIdx.x & 63;
    const float* p = src + row * CDIM + lane * 8;
    f32x4 a0 = *(const f32x4*)p, a1 = *(const f32x4*)(p + 4);
    float s = 0.f, ss = 0.f;
#pragma unroll
    for (int k = 0; k < 4; ++k) { s += a0[k] + a1[k]; ss += a0[k] * a0[k] + a1[k] * a1[k]; }
    s = wsum(s); ss = wsum(ss);
    const float mean = s * (1.0f / 512), var = ss * (1.0f / 512) - mean * mean;
    const float rstd = rsqrtf(var + 1e-5f);
    const float* gp = g + lane * 8;
    const float* bp = bta + lane * 8;
    f32x4 g0 = *(const f32x4*)gp, g1 = *(const f32x4*)(gp + 4);
    f32x4 b0 = *(const f32x4*)bp, b1 = *(const f32x4*)(bp + 4);
    bh8 o;
#pragma unroll
    for (int k = 0; k < 4; ++k) {
        o[k]     = f2bf((a0[k] - mean) * rstd * g0[k] + b0[k]);
        o[k + 4] = f2bf((a1[k] - mean) * rstd * g1[k] + b1[k]);
    }
    *(bh8*)(dst + row * CDIM + lane * 8) = o;
}

// depthwise 3x3 (SAME) + skip + LN(2048) + exact GELU.
// 4 tokens (same row, 4-aligned) per block; coalesced transposed weights.
__global__ __launch_bounds__(256)
void k_dwlngelu4(const bf16* __restrict__ a, const float* __restrict__ dwwT,
                 const float* __restrict__ dwb, const float* __restrict__ g1,
                 const float* __restrict__ b1, bf16* __restrict__ ax)
{
    const long s0 = (long)blockIdx.x * 4;       // quad-base token (quarter-local)
    const int h = (int)((s0 >> 6) & 63);        // row within image (batch bdry is 64-aligned)
    const int w0 = (int)(s0 & 63);              // 4-aligned column
    const int ch = threadIdx.x * 8;

    float wgt[9][8];
#pragma unroll
    for (int kk = 0; kk < 9; ++kk) {
        f32x4 w0v = *(const f32x4*)(dwwT + kk * HIDD + ch);
        f32x4 w1v = *(const f32x4*)(dwwT + kk * HIDD + ch + 4);
#pragma unroll
        for (int j = 0; j < 4; ++j) { wgt[kk][j] = w0v[j]; wgt[kk][j + 4] = w1v[j]; }
    }
#pragma unroll
    for (int j = 0; j < 8; ++j) wgt[4][j] += 1.0f;   // fold the skip (dw + a)

    float acc[4][8];
    {
        f32x4 d0 = *(const f32x4*)(dwb + ch), d1 = *(const f32x4*)(dwb + ch + 4);
#pragma unroll
        for (int ti = 0; ti < 4; ++ti)
#pragma unroll
            for (int j = 0; j < 4; ++j) { acc[ti][j] = d0[j]; acc[ti][j + 4] = d1[j]; }
    }

#pragma unroll
    for (int dy = -1; dy <= 1; ++dy) {
        const int hh = h + dy;
        if ((unsigned)hh >= 64u) continue;       // wave-uniform
#pragma unroll
        for (int c = -1; c <= 4; ++c) {
            const int ww = w0 + c;
            if ((unsigned)ww >= 64u) continue;   // wave-uniform
            bh8 v = *(const bh8*)(a + (s0 + (long)dy * 64 + c) * HIDD + ch);
            float f[8];
#pragma unroll
            for (int j = 0; j < 8; ++j) f[j] = bf2f(v[j]);
#pragma unroll
            for (int ti = 0; ti < 4; ++ti) {
                const int dx = c - ti;
                if (dx < -1 || dx > 1) continue;
                const int kk = (dy + 1) * 3 + (dx + 1);
#pragma unroll
                for (int j = 0; j < 8; ++j) acc[ti][j] += wgt[kk][j] * f[j];
            }
        }
    }

    // LN(2048) per token
    float sv[4], qv[4];
#pragma unroll
    for (int ti = 0; ti < 4; ++ti) {
        float s = 0.f, q = 0.f;
#pragma unroll
        for (int j = 0; j < 8; ++j) { s += acc[ti][j]; q += acc[ti][j] * acc[ti][j]; }
        sv[ti] = wsum(s); qv[ti] = wsum(q);
    }
    __shared__ float red[4][4][2];
    const int wid = threadIdx.x >> 6, lane = threadIdx.x & 63;
    if (lane == 0)
#pragma unroll
        for (int ti = 0; ti < 4; ++ti) { red[wid][ti][0] = sv[ti]; red[wid][ti][1] = qv[ti]; }
    __syncthreads();

    f32x4 ga = *(const f32x4*)(g1 + ch), gb = *(const f32x4*)(g1 + ch + 4);
    f32x4 ba = *(const f32x4*)(b1 + ch), bb = *(const f32x4*)(b1 + ch + 4);
    float gg[8], bb8[8];
#pragma unroll
    for (int j = 0; j < 4; ++j) { gg[j] = ga[j]; gg[j + 4] = gb[j]; bb8[j] = ba[j]; bb8[j + 4] = bb[j]; }

#pragma unroll
    for (int ti = 0; ti < 4; ++ti) {
        const float s = red[0][ti][0] + red[1][ti][0] + red[2][ti][0] + red[3][ti][0];
        const float q = red[0][ti][1] + red[1][ti][1] + red[2][ti][1] + red[3][ti][1];
        const float mean = s * (1.0f / 2048), var = q * (1.0f / 2048) - mean * mean;
        const float rstd = rsqrtf(var + 1e-5f);
        bh8 o;
#pragma unroll
        for (int j = 0; j < 8; ++j) {
            float y = (acc[ti][j] - mean) * rstd * gg[j] + bb8[j];
            o[j] = f2bf(0.5f * y * (1.0f + erff(y * 0.70710678118654752f)));
        }
        *(bh8*)(ax + (s0 + ti) * HIDD + ch) = o;
    }
}

// ---------------------------------------------------------------- launch
extern "C" void kernel_launch(void* const* d_in, const int* in_sizes, int n_in,
                              void* d_out, int out_size, void* d_ws, size_t ws_size,
                              hipStream_t stream) {
    const float* x     = (const float*)d_in[0];
    const float* Wq    = (const float*)d_in[1];
    const float* bq    = (const float*)d_in[2];
    const float* Wk    = (const float*)d_in[3];
    const float* bk    = (const float*)d_in[4];
    const float* Wv    = (const float*)d_in[5];
    const float* bv    = (const float*)d_in[6];
    const float* scale = (const float*)d_in[7];
    const float* fc1_w = (const float*)d_in[8];
    const float* fc1_b = (const float*)d_in[9];
    const float* dw_w  = (const float*)d_in[10];
    const float* dw_b  = (const float*)d_in[11];
    const float* fc2_w = (const float*)d_in[12];
    const float* fc2_b = (const float*)d_in[13];
    const float* ln1_g = (const float*)d_in[14];
    const float* ln1_b = (const float*)d_in[15];
    const float* lnm_g = (const float*)d_in[16];
    const float* lnm_b = (const float*)d_in[17];
    float* out = (float*)d_out;
    char* p = (char*)d_ws;

    // ---- workspace layout (qraw / kv-partials / enhanced live in d_out) ----
    bf16*  xbT   = (bf16*)(p + 0);            // 32 MiB: x^T  -> later qb
    bf16*  kb    = (bf16*)(p + 33554432);     // 32 MiB: conv-k (bf16), softmax in-place
    bf16*  vb    = (bf16*)(p + 67108864);     // 32 MiB: conv-v
    bf16*  kvt   = (bf16*)(p + 100663296);    //  4 MiB: kv^T (B,512,512)
    bf16*  wqb   = (bf16*)(p + 104857600);
    bf16*  wkb   = (bf16*)(p + 105381888);
    bf16*  wvb   = (bf16*)(p + 105906176);
    bf16*  fc1wT = (bf16*)(p + 106430464);    //  2 MiB
    bf16*  fc2wT = (bf16*)(p + 108527616);    //  2 MiB
    float* invsc = (float*)(p + 110624768);
    float* dwwT  = (float*)(p + 110626816);   // 73,728 B
    float* qsum  = (float*)(p + 110757888);
    float* kpartX= (float*)(p + 110774272);   // (unused; layout clarity)
    float* ksum  = (float*)(p + 110905344);
    float* zbuf  = (float*)(p + 110921728);
    const size_t REQUIRED = 111052800;
    // overlays: qpart/kpart live in the kvt region (dead until kv GEMM)
    float* qpart = (float*)kvt;               // 8*16*512*4 = 262,144 B
    float* kpart = (float*)((char*)kvt + 262144);   // 262,144 B
    // FFN-phase overlays (quarter = 2 batches = 8192 tokens):
    bf16*  qb    = xbT;                       // after convs, xbT dead
    bf16*  abuf  = (bf16*)(p + 0);            // after attn, qb dead (32 MiB)
    bf16*  axbuf = (bf16*)(p + 33554432);     // kb dead (32 MiB)
    bf16*  tbuf  = (bf16*)(p + 67108864);     // vb dead (8 MiB used)

    if (ws_size < REQUIRED) {   // sentinel encodes actual ws size in MiB
        k_fill<<<(out_size + 255) / 256, 256, 0, stream>>>(out, out_size, 100000.0f + (float)(ws_size >> 20));
        return;
    }
    (void)kpartX;

    const long NC = (long)NDIM * CDIM;  // 2,097,152 elements per batch

    // pack / convert params
    k_cvt_bf16<<<1024, 256, 0, stream>>>(Wq, wqb, 262144);
    k_cvt_bf16<<<1024, 256, 0, stream>>>(Wk, wkb, 262144);
    k_cvt_bf16<<<1024, 256, 0, stream>>>(Wv, wvb, 262144);
    k_transpose<<<dim3(32, 8, 1), 256, 0, stream>>>(fc1_w, fc1wT, 2048, 512, 0, 0);
    k_transpose<<<dim3(8, 32, 1), 256, 0, stream>>>(fc2_w, fc2wT, 512, 2048, 0, 0);
    k_invsc<<<1, 512, 0, stream>>>(scale, invsc);
    k_transpose<<<dim3(64, 8, BATCH), 256, 0, stream>>>(x, xbT, 4096, 512, NC, NC);

    // conv1x1 GEMMs: out[b](C=512, s=4096) = W @ x[b]; flat == raw (B,N,C) view
    gemm_bt<EP_F32_BROW><<<dim3(32, 4, 8), 256, 0, stream>>>(wqb, 512, 0, xbT, 512, NC, out, 4096, NC, 512, bq, nullptr, 0, nullptr, 0);
    gemm_bt<EP_BF16_BROW><<<dim3(32, 4, 8), 256, 0, stream>>>(wkb, 512, 0, xbT, 512, NC, kb, 4096, NC, 512, bk, nullptr, 0, nullptr, 0);
    gemm_bt<EP_BF16_BROW><<<dim3(32, 4, 8), 256, 0, stream>>>(wvb, 512, 0, xbT, 512, NC, vb, 4096, NC, 512, bv, nullptr, 0, nullptr, 0);

    // q/k nonlinear chains (qraw f32 lives in `out`)
    k_qcol_partial<<<dim3(2, 16, 8), 256, 0, stream>>>(out, qpart);
    k_qcol_reduce<<<16, 256, 0, stream>>>(qpart, qsum);
    k_qrow<<<8192, 256, 0, stream>>>(out, qsum, invsc, qb);
    k_krow<<<8192, 256, 0, stream>>>(kb, invsc);
    k_colsum_part<<<dim3(16, 8), 256, 0, stream>>>(kb, kpart);
    k_colsum_red<<<16, 256, 0, stream>>>(kpart, ksum);
    k_z<<<8192, 256, 0, stream>>>(qb, ksum, zbuf);

    // kv^T[b,d,c] = sum_j v[b,j,d] k[b,j,c]  — split-K x8; partials in `out`
    // (qraw there is dead after k_qrow; EP_ATTN fully overwrites `out` after)
    gemm_tn_splitk<<<dim3(4, 4, 64), 256, 0, stream>>>(vb, 512, NC, kb, 512, NC, out);
    k_kvred<<<2048, 256, 0, stream>>>(out, kvt);
    // enhanced = shortcut + z*(q@kv)  -> overwrites partials in `out`
    gemm_bt<EP_ATTN><<<dim3(4, 32, 8), 256, 0, stream>>>(qb, 512, NC, kvt, 512, 262144, out, 512, NC, 512, nullptr, x, NC, zbuf, 4096);

    // MixFFN in 4 quarters (2 batches each) over dead attention buffers
    k_dwT<<<72, 256, 0, stream>>>(dw_w, dwwT);
    for (int q4 = 0; q4 < 4; ++q4) {
        float* outq = out + (long)q4 * 8192 * CDIM;
        k_ln512<<<2048, 256, 0, stream>>>(outq, lnm_g, lnm_b, tbuf);
        gemm_bt<EP_BF16_BCOL><<<dim3(16, 64, 1), 256, 0, stream>>>(tbuf, 512, 0, fc1wT, 512, 0, abuf, 2048, 0, 512, fc1_b, nullptr, 0, nullptr, 0);
        k_dwlngelu4<<<2048, 256, 0, stream>>>(abuf, dwwT, dw_b, ln1_g, ln1_b, axbuf);
        gemm_bt<EP_OUT><<<dim3(4, 64, 1), 256, 0, stream>>>(axbuf, 2048, 0, fc2wT, 2048, 0, outq, 512, 0, 2048, fc2_b, outq, 0, nullptr, 0);
    }
}

// Round 5
// 741.977 us; speedup vs baseline: 1.6534x; 1.0463x over previous
//
#include <hip/hip_runtime.h>
#include <hip/hip_bf16.h>

typedef __hip_bfloat16 bf16;
typedef __attribute__((ext_vector_type(8))) short bh8;      // 8 x bf16 bits
typedef __attribute__((ext_vector_type(4))) short bh4;      // 4 x bf16 bits
typedef __attribute__((ext_vector_type(4))) float f32x4;

#define CDIM 512
#define NDIM 4096
#define HIDD 2048
#define BATCH 8

__device__ __forceinline__ float bf2f(short s) {
    union { unsigned u; float f; } c; c.u = ((unsigned)(unsigned short)s) << 16; return c.f;
}
__device__ __forceinline__ short f2bf(float f) {
    union { __hip_bfloat16 h; short s; } c; c.h = __float2bfloat16(f); return c.s;
}
__device__ __forceinline__ float wsum(float v) {
#pragma unroll
    for (int o = 32; o; o >>= 1) v += __shfl_xor(v, o);
    return v;
}
__device__ __forceinline__ float wmax(float v) {
#pragma unroll
    for (int o = 32; o; o >>= 1) v = fmaxf(v, __shfl_xor(v, o));
    return v;
}

#define GLL(g, l) __builtin_amdgcn_global_load_lds( \
    (const __attribute__((address_space(1))) unsigned int*)(g), \
    (__attribute__((address_space(3))) unsigned int*)(l), 16, 0, 0)

// XCD-aware bijective block swizzle (T1): contiguous work-chunk per XCD.
// Requires nwg % 8 == 0 (all our grids satisfy this).
__device__ __forceinline__ void xcd_swz(int& bx, int& by, int& bz) {
    const int gx = gridDim.x, gy = gridDim.y;
    const int nwg = gx * gy * gridDim.z;
    int lid = blockIdx.x + gx * (blockIdx.y + gy * blockIdx.z);
    const int cpx = nwg >> 3;
    int swz = (lid & 7) * cpx + (lid >> 3);
    bx = swz % gx; swz /= gx;
    by = swz % gy;
    bz = swz / gy;
}

// ---------------------------------------------------------------- GEMM (NT)
// C[M,N] = A(M,K) @ Bt(N,K)^T, row-major bf16, fp32 accum. 128x128 tile, BK=64.
enum { EP_QEXP = 0, EP_BF16_BROW = 1, EP_ATTN = 3, EP_BF16_BCOL = 4, EP_OUT = 5 };

template<int MODE>
__global__ __launch_bounds__(256)
void gemm_bt(const bf16* __restrict__ A, int lda, long sA,
             const bf16* __restrict__ Bt, int ldb, long sB,
             void* __restrict__ Cp, int ldc, long sC, int K,
             const float* __restrict__ bias,
             const float* __restrict__ aux1, long sAux1,
             const float* __restrict__ aux2, long sAux2)
{
    __shared__ __align__(16) bf16 As[128 * 64];
    __shared__ __align__(16) bf16 Bs[128 * 64];
    int bx, by, bz;
    xcd_swz(bx, by, bz);
    const bf16* Ab = A + (long)bz * sA + (long)by * 128 * lda;
    const bf16* Bb = Bt + (long)bz * sB + (long)bx * 128 * ldb;
    const int t = threadIdx.x, lane = t & 63, wid = t >> 6;
    const int wm = wid >> 1, wn = wid & 1, lg = lane >> 4, lr = lane & 15;

    f32x4 acc[4][4];
#pragma unroll
    for (int m = 0; m < 4; ++m)
#pragma unroll
        for (int n = 0; n < 4; ++n) acc[m][n] = (f32x4){0.f, 0.f, 0.f, 0.f};

    for (int kt = 0; kt < K; kt += 64) {
#pragma unroll
        for (int i = 0; i < 4; ++i) {
            int ch = i * 256 + t;
            GLL(Ab + (long)(ch >> 3) * lda + kt + ((ch & 7) << 3), (char*)As + i * 4096 + wid * 1024);
            GLL(Bb + (long)(ch >> 3) * ldb + kt + ((ch & 7) << 3), (char*)Bs + i * 4096 + wid * 1024);
        }
        __syncthreads();
#pragma unroll
        for (int kk = 0; kk < 2; ++kk) {
            bh8 af[4], bfv[4];
#pragma unroll
            for (int m = 0; m < 4; ++m) af[m] = *(const bh8*)(As + (wm * 64 + m * 16 + lr) * 64 + kk * 32 + lg * 8);
#pragma unroll
            for (int n = 0; n < 4; ++n) bfv[n] = *(const bh8*)(Bs + (wn * 64 + n * 16 + lr) * 64 + kk * 32 + lg * 8);
#pragma unroll
            for (int m = 0; m < 4; ++m)
#pragma unroll
                for (int n = 0; n < 4; ++n)
                    acc[m][n] = __builtin_amdgcn_mfma_f32_16x16x32_bf16(af[m], bfv[n], acc[m][n], 0, 0, 0);
        }
        __syncthreads();
    }

    const int gr0 = by * 128 + wm * 64;
    const int gc0 = bx * 128 + wn * 64;
#pragma unroll
    for (int m = 0; m < 4; ++m) {
#pragma unroll
        for (int n = 0; n < 4; ++n) {
            const int gc = gc0 + n * 16 + lr;
#pragma unroll
            for (int r = 0; r < 4; ++r) {
                const int gr = gr0 + m * 16 + lg * 4 + r;
                float v = acc[m][n][r];
                if constexpr (MODE == EP_QEXP) {
                    // conv-q: store exp(raw) as bf16 (consumed by softmax chain)
                    ((bf16*)Cp + (long)bz * sC)[(long)gr * ldc + gc] = __float2bfloat16(expf(v + bias[gr]));
                } else if constexpr (MODE == EP_BF16_BROW) {
                    ((bf16*)Cp + (long)bz * sC)[(long)gr * ldc + gc] = __float2bfloat16(v + bias[gr]);
                } else if constexpr (MODE == EP_ATTN) {
                    const float* xg = aux1 + (long)bz * sAux1;   // x[b] (C, N): shortcut
                    const float* zg = aux2 + (long)bz * sAux2;   // z[b] (N)
                    ((float*)Cp + (long)bz * sC)[(long)gr * ldc + gc] = zg[gr] * v + xg[(long)gc * NDIM + gr];
                } else if constexpr (MODE == EP_BF16_BCOL) {
                    ((bf16*)Cp + (long)bz * sC)[(long)gr * ldc + gc] = __float2bfloat16(v + bias[gc]);
                } else { // EP_OUT: out = acc + bias[col] + out (in-place residual)
                    float* op = (float*)Cp;
                    const long idx = (long)gr * ldc + gc;
                    op[idx] = v + bias[gc] + aux1[idx];
                }
            }
        }
    }
}

// ---------------------------------------------------------------- GEMM (TN, split-K x4)
// part[b,ks] (512x512) = A[b,ks-chunk]^T @ B[b,ks-chunk];  A,B: (4096 x 512) row-major.
// Grid (4, 4, 8*4): z = b*4 + ks, each handles K-chunk of 1024.
// XOR-swizzled staging (source-side) -> conflict-free column-fragment reads.
__global__ __launch_bounds__(256)
void gemm_tn_splitk(const bf16* __restrict__ A, int lda, long sA,
                    const bf16* __restrict__ B, int ldb, long sB,
                    float* __restrict__ part)
{
    __shared__ __align__(16) short As[64 * 128];
    __shared__ __align__(16) short Bs[64 * 128];
    int bx, by, bzl;
    xcd_swz(bx, by, bzl);
    const int bz = bzl >> 2, ks = bzl & 3;
    const bf16* Ab = A + (long)bz * sA + (long)ks * 1024 * lda + by * 128;
    const bf16* Bb = B + (long)bz * sB + (long)ks * 1024 * ldb + bx * 128;
    const int t = threadIdx.x, lane = t & 63, wid = t >> 6;
    const int wm = wid >> 1, wn = wid & 1, lg = lane >> 4, lr = lane & 15;

    f32x4 acc[4][4];
#pragma unroll
    for (int m = 0; m < 4; ++m)
#pragma unroll
        for (int n = 0; n < 4; ++n) acc[m][n] = (f32x4){0.f, 0.f, 0.f, 0.f};

    for (int kt = 0; kt < 1024; kt += 64) {
#pragma unroll
        for (int i = 0; i < 4; ++i) {
            const int ch = i * 256 + t;                 // linear 16B-chunk id
            const int row = ch >> 4;                    // k within tile
            const int cs = (ch & 15) ^ (((row >> 3) & 3) << 1);  // swizzled src chunk
            GLL(Ab + (long)(kt + row) * lda + (cs << 3), (char*)As + i * 4096 + wid * 1024);
            GLL(Bb + (long)(kt + row) * ldb + (cs << 3), (char*)Bs + i * 4096 + wid * 1024);
        }
        __syncthreads();
#pragma unroll
        for (int kk = 0; kk < 2; ++kk) {
            bh8 af[4], bfv[4];
#pragma unroll
            for (int m = 0; m < 4; ++m) {
                const int col = wm * 64 + m * 16 + lr;
#pragma unroll
                for (int u = 0; u < 8; ++u) {
                    const int row = kk * 32 + lg * 8 + u;
                    af[m][u] = As[row * 128 + (((col >> 3) ^ (((row >> 3) & 3) << 1)) << 3) + (col & 7)];
                }
            }
#pragma unroll
            for (int n = 0; n < 4; ++n) {
                const int col = wn * 64 + n * 16 + lr;
#pragma unroll
                for (int u = 0; u < 8; ++u) {
                    const int row = kk * 32 + lg * 8 + u;
                    bfv[n][u] = Bs[row * 128 + (((col >> 3) ^ (((row >> 3) & 3) << 1)) << 3) + (col & 7)];
                }
            }
#pragma unroll
            for (int m = 0; m < 4; ++m)
#pragma unroll
                for (int n = 0; n < 4; ++n)
                    acc[m][n] = __builtin_amdgcn_mfma_f32_16x16x32_bf16(af[m], bfv[n], acc[m][n], 0, 0, 0);
        }
        __syncthreads();
    }

    float* po = part + ((long)bzl << 18);               // 512*512 per (b,ks)
    const int gr0 = by * 128 + wm * 64;
    const int gc0 = bx * 128 + wn * 64;
#pragma unroll
    for (int m = 0; m < 4; ++m)
#pragma unroll
        for (int n = 0; n < 4; ++n) {
            const int gc = gc0 + n * 16 + lr;
#pragma unroll
            for (int r = 0; r < 4; ++r) {
                const int gr = gr0 + m * 16 + lg * 4 + r;
                po[(long)gr * 512 + gc] = acc[m][n][r];
            }
        }
}

// kvt[b] = bf16( sum_ks part[b,ks] )   — 4 elems/thread, vectorized.
__global__ __launch_bounds__(256)
void k_kvred(const float* __restrict__ part, bf16* __restrict__ kvt)
{
    const long e = ((long)blockIdx.x * 256 + threadIdx.x) * 4;
    const int b = (int)(e >> 18);
    const int off = (int)(e & 262143);
    f32x4 s = (f32x4){0.f, 0.f, 0.f, 0.f};
#pragma unroll
    for (int ks = 0; ks < 4; ++ks) {
        f32x4 v = *(const f32x4*)(part + (((long)(b * 4 + ks)) << 18) + off);
        s = s + v;
    }
    bh4 o;
#pragma unroll
    for (int j = 0; j < 4; ++j) o[j] = f2bf(s[j]);
    *(bh4*)(kvt + ((long)b << 18) + off) = o;
}

// ---------------------------------------------------------------- transpose
__global__ __launch_bounds__(256)
void k_transpose(const float* __restrict__ src, bf16* __restrict__ dst,
                 int Rd, int Cd, long sSrc, long sDst)
{
    __shared__ float tile[64][65];
    const float* s = src + (long)blockIdx.z * sSrc;
    bf16* d = dst + (long)blockIdx.z * sDst;
    const int r0 = blockIdx.x * 64, c0 = blockIdx.y * 64;
    const int t = threadIdx.x;
#pragma unroll 4
    for (int i = 0; i < 16; ++i) {
        int idx = i * 256 + t;
        int a = idx >> 6, b = idx & 63;
        tile[a][b] = s[(long)(c0 + a) * Rd + r0 + b];
    }
    __syncthreads();
#pragma unroll 4
    for (int i = 0; i < 16; ++i) {
        int idx = i * 256 + t;
        int a = idx >> 6, b = idx & 63;
        d[(long)(r0 + a) * Cd + c0 + b] = __float2bfloat16(tile[b][a]);
    }
}

__global__ void k_cvt_bf16(const float* __restrict__ in, bf16* __restrict__ out, int n) {
    int i = blockIdx.x * 256 + threadIdx.x;
    if (i < n) out[i] = __float2bfloat16(in[i]);
}

__global__ void k_invsc(const float* __restrict__ scale, float* __restrict__ invsc) {
    int j = threadIdx.x;
    invsc[j] = 1.0f / log1pf(expf(scale[j]));   // 1/softplus(scale)
}

__global__ void k_fill(float* o, int n, float v) {
    int i = blockIdx.x * 256 + threadIdx.x; if (i < n) o[i] = v;
}

// dw weights (2048,1,3,3) -> transposed [9][2048] f32
__global__ void k_dwT(const float* __restrict__ w, float* __restrict__ wT) {
    int i = blockIdx.x * 256 + threadIdx.x;
    if (i < HIDD * 9) {
        int chn = i / 9, kk = i % 9;
        wT[kk * HIDD + chn] = w[i];
    }
}

// ------------------------------------------------- q column-softmax denom
// qe holds bf16 exp(conv_q); column j = stride-CDIM walk of flat buf.
__global__ __launch_bounds__(256)
void k_qcol_partial(const bf16* __restrict__ qe, float* __restrict__ qpart) {
    const int j = blockIdx.x * 256 + threadIdx.x;
    const int ic = blockIdx.y, b = blockIdx.z;     // 16 chunks of 256 rows
    const bf16* p = qe + (long)b * (NDIM * CDIM) + (long)ic * 256 * CDIM + j;
    float s = 0.f;
    for (int i = 0; i < 256; ++i) s += bf2f(*(const short*)(p + (long)i * CDIM));
    qpart[((long)b * 16 + ic) * CDIM + j] = s;
}
__global__ __launch_bounds__(256)
void k_qcol_reduce(const float* __restrict__ qpart, float* __restrict__ qsum) {
    const int idx = blockIdx.x * 256 + threadIdx.x;  // B*C = 4096
    const int b = idx >> 9, j = idx & 511;
    float s = 0.f;
#pragma unroll
    for (int ic = 0; ic < 16; ++ic) s += qpart[((long)b * 16 + ic) * CDIM + j];
    qsum[idx] = s;
}

// q row pass: p=(qe/colsum + 1e-6)/sc, keep ||p||, cube, renorm -> bf16
__global__ __launch_bounds__(256)
void k_qrow(const bf16* __restrict__ qe, const float* __restrict__ qsum,
            const float* __restrict__ invsc, bf16* __restrict__ qb)
{
    const long row = (long)blockIdx.x * 4 + (threadIdx.x >> 6);
    const int lane = threadIdx.x & 63;
    const int b = (int)(row >> 12);
    bh8 ev = *(const bh8*)(qe + row * CDIM + lane * 8);
    const float* qs = qsum + b * CDIM + lane * 8;
    const float* is = invsc + lane * 8;
    f32x4 s0 = *(const f32x4*)qs, s1 = *(const f32x4*)(qs + 4);
    f32x4 i0 = *(const f32x4*)is, i1 = *(const f32x4*)(is + 4);
    float q[8];
#pragma unroll
    for (int k = 0; k < 4; ++k) {
        q[k]     = (bf2f(ev[k]) / s0[k] + 1e-6f) * i0[k];
        q[k + 4] = (bf2f(ev[k + 4]) / s1[k] + 1e-6f) * i1[k];
    }
    float s2 = 0.f, s6 = 0.f, q3[8];
#pragma unroll
    for (int k = 0; k < 8; ++k) { s2 += q[k] * q[k]; float c = q[k] * q[k] * q[k]; q3[k] = c; s6 += c * c; }
    s2 = wsum(s2); s6 = wsum(s6);
    const float sc = sqrtf(s2) / sqrtf(s6);
    bh8 o;
#pragma unroll
    for (int k = 0; k < 8; ++k) o[k] = f2bf(q3[k] * sc);
    *(bh8*)(qb + row * CDIM + lane * 8) = o;
}

// k row pass (IN-PLACE, bf16): row softmax (axis=2), /sc, cube, renorm.
__global__ __launch_bounds__(256)
void k_krow(bf16* __restrict__ kb, const float* __restrict__ invsc)
{
    const long row = (long)blockIdx.x * 4 + (threadIdx.x >> 6);
    const int lane = threadIdx.x & 63;
    bh8 v = *(const bh8*)(kb + row * CDIM + lane * 8);
    const float* is = invsc + lane * 8;
    f32x4 i0 = *(const f32x4*)is, i1 = *(const f32x4*)(is + 4);
    float xv[8];
#pragma unroll
    for (int k = 0; k < 8; ++k) xv[k] = bf2f(v[k]);
    float mx = -1e30f;
#pragma unroll
    for (int k = 0; k < 8; ++k) mx = fmaxf(mx, xv[k]);
    mx = wmax(mx);
    float e[8], se = 0.f;
#pragma unroll
    for (int k = 0; k < 8; ++k) { e[k] = expf(xv[k] - mx); se += e[k]; }
    se = wsum(se);
    const float inv = 1.0f / se;
    float q[8];
#pragma unroll
    for (int k = 0; k < 4; ++k) {
        q[k]     = (e[k] * inv + 1e-6f) * i0[k];
        q[k + 4] = (e[k + 4] * inv + 1e-6f) * i1[k];
    }
    float s2 = 0.f, s6 = 0.f, q3[8];
#pragma unroll
    for (int k = 0; k < 8; ++k) { s2 += q[k] * q[k]; float c = q[k] * q[k] * q[k]; q3[k] = c; s6 += c * c; }
    s2 = wsum(s2); s6 = wsum(s6);
    const float sc = sqrtf(s2) / sqrtf(s6);
    bh8 o;
#pragma unroll
    for (int k = 0; k < 8; ++k) o[k] = f2bf(q3[k] * sc);
    *(bh8*)(kb + row * CDIM + lane * 8) = o;
}

// ksum[b,c] = sum_j kb[b,j,c] : two-stage column sum, 16 chunks of 256 rows.
__global__ __launch_bounds__(256)
void k_colsum_part(const bf16* __restrict__ kb, float* __restrict__ part) {
    const int b = blockIdx.y, jc = blockIdx.x, t = threadIdx.x;
    const bf16* p = kb + (long)b * (NDIM * CDIM) + (long)jc * 256 * CDIM + t * 2;
    float s0 = 0.f, s1 = 0.f;
    for (int j = 0; j < 256; ++j) {
        unsigned u = *(const unsigned*)(p + (long)j * CDIM);
        s0 += bf2f((short)(u & 0xffff));
        s1 += bf2f((short)(u >> 16));
    }
    float* o = part + ((long)b * 16 + jc) * CDIM + t * 2;
    o[0] = s0; o[1] = s1;
}
__global__ __launch_bounds__(256)
void k_colsum_red(const float* __restrict__ part, float* __restrict__ ksum) {
    const int idx = blockIdx.x * 256 + threadIdx.x;  // 4096
    const int b = idx >> 9, c = idx & 511;
    float s = 0.f;
#pragma unroll
    for (int jc = 0; jc < 16; ++jc) s += part[((long)b * 16 + jc) * CDIM + c];
    ksum[idx] = s;
}

// z[b,i] = 1/(q[i,:].ksum[b,:] + 1e-6)
__global__ __launch_bounds__(256)
void k_z(const bf16* __restrict__ qb, const float* __restrict__ ksum, float* __restrict__ z)
{
    const long row = (long)blockIdx.x * 4 + (threadIdx.x >> 6);
    const int lane = threadIdx.x & 63;
    const int b = (int)(row >> 12);
    bh8 q = *(const bh8*)(qb + row * CDIM + lane * 8);
    const float* ks = ksum + (long)b * CDIM + lane * 8;
    f32x4 k0 = *(const f32x4*)ks, k1 = *(const f32x4*)(ks + 4);
    float s = 0.f;
#pragma unroll
    for (int j = 0; j < 4; ++j) { s += bf2f(q[j]) * k0[j]; s += bf2f(q[j + 4]) * k1[j]; }
    s = wsum(s);
    if (lane == 0) z[row] = 1.0f / (s + 1e-6f);
}

// LN over 512 (lnm), fp32 in -> bf16 out. 1 wave/row.
__global__ __launch_bounds__(256)
void k_ln512(const float* __restrict__ src, const float* __restrict__ g,
             const float* __restrict__ bta, bf16* __restrict__ dst)
{
    const long row = (long)blockIdx.x * 4 + (threadIdx.x >> 6);
    const int lane = threadIdx.x & 63;
    const float* p = src + row * CDIM + lane * 8;
    f32x4 a0 = *(const f32x4*)p, a1 = *(const f32x4*)(p + 4);
    float s = 0.f, ss = 0.f;
#pragma unroll
    for (int k = 0; k < 4; ++k) { s += a0[k] + a1[k]; ss += a0[k] * a0[k] + a1[k] * a1[k]; }
    s = wsum(s); ss = wsum(ss);
    const float mean = s * (1.0f / 512), var = ss * (1.0f / 512) - mean * mean;
    const float rstd = rsqrtf(var + 1e-5f);
    const float* gp = g + lane * 8;
    const float* bp = bta + lane * 8;
    f32x4 g0 = *(const f32x4*)gp, g1 = *(const f32x4*)(gp + 4);
    f32x4 b0 = *(const f32x4*)bp, b1 = *(const f32x4*)(bp + 4);
    bh8 o;
#pragma unroll
    for (int k = 0; k < 4; ++k) {
        o[k]     = f2bf((a0[k] - mean) * rstd * g0[k] + b0[k]);
        o[k + 4] = f2bf((a1[k] - mean) * rstd * g1[k] + b1[k]);
    }
    *(bh8*)(dst + row * CDIM + lane * 8) = o;
}

// depthwise 3x3 (SAME) + skip + LN(2048) + exact GELU.
// 4 tokens (same row, 4-aligned) per block; coalesced transposed weights.
__global__ __launch_bounds__(256)
void k_dwlngelu4(const bf16* __restrict__ a, const float* __restrict__ dwwT,
                 const float* __restrict__ dwb, const float* __restrict__ g1,
                 const float* __restrict__ b1, bf16* __restrict__ ax)
{
    const long s0 = (long)blockIdx.x * 4;       // quad-base token (quarter-local)
    const int h = (int)((s0 >> 6) & 63);        // row within image (batch bdry is 64-aligned)
    const int w0 = (int)(s0 & 63);              // 4-aligned column
    const int ch = threadIdx.x * 8;

    float wgt[9][8];
#pragma unroll
    for (int kk = 0; kk < 9; ++kk) {
        f32x4 w0v = *(const f32x4*)(dwwT + kk * HIDD + ch);
        f32x4 w1v = *(const f32x4*)(dwwT + kk * HIDD + ch + 4);
#pragma unroll
        for (int j = 0; j < 4; ++j) { wgt[kk][j] = w0v[j]; wgt[kk][j + 4] = w1v[j]; }
    }
#pragma unroll
    for (int j = 0; j < 8; ++j) wgt[4][j] += 1.0f;   // fold the skip (dw + a)

    float acc[4][8];
    {
        f32x4 d0 = *(const f32x4*)(dwb + ch), d1 = *(const f32x4*)(dwb + ch + 4);
#pragma unroll
        for (int ti = 0; ti < 4; ++ti)
#pragma unroll
            for (int j = 0; j < 4; ++j) { acc[ti][j] = d0[j]; acc[ti][j + 4] = d1[j]; }
    }

#pragma unroll
    for (int dy = -1; dy <= 1; ++dy) {
        const int hh = h + dy;
        if ((unsigned)hh >= 64u) continue;       // wave-uniform
#pragma unroll
        for (int c = -1; c <= 4; ++c) {
            const int ww = w0 + c;
            if ((unsigned)ww >= 64u) continue;   // wave-uniform
            bh8 v = *(const bh8*)(a + (s0 + (long)dy * 64 + c) * HIDD + ch);
            float f[8];
#pragma unroll
            for (int j = 0; j < 8; ++j) f[j] = bf2f(v[j]);
#pragma unroll
            for (int ti = 0; ti < 4; ++ti) {
                const int dx = c - ti;
                if (dx < -1 || dx > 1) continue;
                const int kk = (dy + 1) * 3 + (dx + 1);
#pragma unroll
                for (int j = 0; j < 8; ++j) acc[ti][j] += wgt[kk][j] * f[j];
            }
        }
    }

    // LN(2048) per token
    float sv[4], qv[4];
#pragma unroll
    for (int ti = 0; ti < 4; ++ti) {
        float s = 0.f, q = 0.f;
#pragma unroll
        for (int j = 0; j < 8; ++j) { s += acc[ti][j]; q += acc[ti][j] * acc[ti][j]; }
        sv[ti] = wsum(s); qv[ti] = wsum(q);
    }
    __shared__ float red[4][4][2];
    const int wid = threadIdx.x >> 6, lane = threadIdx.x & 63;
    if (lane == 0)
#pragma unroll
        for (int ti = 0; ti < 4; ++ti) { red[wid][ti][0] = sv[ti]; red[wid][ti][1] = qv[ti]; }
    __syncthreads();

    f32x4 ga = *(const f32x4*)(g1 + ch), gb = *(const f32x4*)(g1 + ch + 4);
    f32x4 ba = *(const f32x4*)(b1 + ch), bb = *(const f32x4*)(b1 + ch + 4);
    float gg[8], bb8[8];
#pragma unroll
    for (int j = 0; j < 4; ++j) { gg[j] = ga[j]; gg[j + 4] = gb[j]; bb8[j] = ba[j]; bb8[j + 4] = bb[j]; }

#pragma unroll
    for (int ti = 0; ti < 4; ++ti) {
        const float s = red[0][ti][0] + red[1][ti][0] + red[2][ti][0] + red[3][ti][0];
        const float q = red[0][ti][1] + red[1][ti][1] + red[2][ti][1] + red[3][ti][1];
        const float mean = s * (1.0f / 2048), var = q * (1.0f / 2048) - mean * mean;
        const float rstd = rsqrtf(var + 1e-5f);
        bh8 o;
#pragma unroll
        for (int j = 0; j < 8; ++j) {
            float y = (acc[ti][j] - mean) * rstd * gg[j] + bb8[j];
            o[j] = f2bf(0.5f * y * (1.0f + erff(y * 0.70710678118654752f)));
        }
        *(bh8*)(ax + (s0 + ti) * HIDD + ch) = o;
    }
}

// ---------------------------------------------------------------- launch
extern "C" void kernel_launch(void* const* d_in, const int* in_sizes, int n_in,
                              void* d_out, int out_size, void* d_ws, size_t ws_size,
                              hipStream_t stream) {
    const float* x     = (const float*)d_in[0];
    const float* Wq    = (const float*)d_in[1];
    const float* bq    = (const float*)d_in[2];
    const float* Wk    = (const float*)d_in[3];
    const float* bk    = (const float*)d_in[4];
    const float* Wv    = (const float*)d_in[5];
    const float* bv    = (const float*)d_in[6];
    const float* scale = (const float*)d_in[7];
    const float* fc1_w = (const float*)d_in[8];
    const float* fc1_b = (const float*)d_in[9];
    const float* dw_w  = (const float*)d_in[10];
    const float* dw_b  = (const float*)d_in[11];
    const float* fc2_w = (const float*)d_in[12];
    const float* fc2_b = (const float*)d_in[13];
    const float* ln1_g = (const float*)d_in[14];
    const float* ln1_b = (const float*)d_in[15];
    const float* lnm_g = (const float*)d_in[16];
    const float* lnm_b = (const float*)d_in[17];
    float* out = (float*)d_out;
    char* p = (char*)d_ws;

    // ---- workspace layout (qe / kv-partials / enhanced live in d_out) ----
    bf16*  xbT   = (bf16*)(p + 0);            // 32 MiB: x^T  -> later qb
    bf16*  kb    = (bf16*)(p + 33554432);     // 32 MiB: conv-k (bf16), softmax in-place
    bf16*  vb    = (bf16*)(p + 67108864);     // 32 MiB: conv-v -> later tbuf (full)
    bf16*  kvt   = (bf16*)(p + 100663296);    //  4 MiB: kv^T (B,512,512)
    bf16*  wqb   = (bf16*)(p + 104857600);
    bf16*  wkb   = (bf16*)(p + 105381888);
    bf16*  wvb   = (bf16*)(p + 105906176);
    bf16*  fc1wT = (bf16*)(p + 106430464);    //  2 MiB
    bf16*  fc2wT = (bf16*)(p + 108527616);    //  2 MiB
    float* invsc = (float*)(p + 110624768);
    float* dwwT  = (float*)(p + 110626816);   // 73,728 B
    float* qsum  = (float*)(p + 110757888);
    float* kpartX= (float*)(p + 110774272);   // (unused; layout clarity)
    float* ksum  = (float*)(p + 110905344);
    float* zbuf  = (float*)(p + 110921728);
    const size_t REQUIRED = 111052800;
    // overlays: qpart/kpart live in the kvt region (dead until kv GEMM)
    float* qpart = (float*)kvt;               // 8*16*512*4 = 262,144 B
    float* kpart = (float*)((char*)kvt + 262144);   // 262,144 B
    // qe: bf16 exp(conv_q) lives in d_out (dead before EP_ATTN overwrites)
    bf16*  qe    = (bf16*)out;                // 64 MiB
    // FFN-phase overlays:
    bf16*  qb    = xbT;                       // after convs, xbT dead
    bf16*  abuf  = (bf16*)(p + 0);            // after attn, qb dead (32 MiB)
    bf16*  axbuf = (bf16*)(p + 33554432);     // kb dead (32 MiB)
    bf16*  tbuf  = (bf16*)(p + 67108864);     // vb dead (32 MiB, full-batch LN out)

    if (ws_size < REQUIRED) {   // sentinel encodes actual ws size in MiB
        k_fill<<<(out_size + 255) / 256, 256, 0, stream>>>(out, out_size, 100000.0f + (float)(ws_size >> 20));
        return;
    }
    (void)kpartX;

    const long NC = (long)NDIM * CDIM;  // 2,097,152 elements per batch

    // pack / convert params
    k_cvt_bf16<<<1024, 256, 0, stream>>>(Wq, wqb, 262144);
    k_cvt_bf16<<<1024, 256, 0, stream>>>(Wk, wkb, 262144);
    k_cvt_bf16<<<1024, 256, 0, stream>>>(Wv, wvb, 262144);
    k_transpose<<<dim3(32, 8, 1), 256, 0, stream>>>(fc1_w, fc1wT, 2048, 512, 0, 0);
    k_transpose<<<dim3(8, 32, 1), 256, 0, stream>>>(fc2_w, fc2wT, 512, 2048, 0, 0);
    k_invsc<<<1, 512, 0, stream>>>(scale, invsc);
    k_transpose<<<dim3(64, 8, BATCH), 256, 0, stream>>>(x, xbT, 4096, 512, NC, NC);

    // conv1x1 GEMMs: out[b](C=512, s=4096) = W @ x[b]; flat == raw (B,N,C) view
    gemm_bt<EP_QEXP><<<dim3(32, 4, 8), 256, 0, stream>>>(wqb, 512, 0, xbT, 512, NC, qe, 4096, NC, 512, bq, nullptr, 0, nullptr, 0);
    gemm_bt<EP_BF16_BROW><<<dim3(32, 4, 8), 256, 0, stream>>>(wkb, 512, 0, xbT, 512, NC, kb, 4096, NC, 512, bk, nullptr, 0, nullptr, 0);
    gemm_bt<EP_BF16_BROW><<<dim3(32, 4, 8), 256, 0, stream>>>(wvb, 512, 0, xbT, 512, NC, vb, 4096, NC, 512, bv, nullptr, 0, nullptr, 0);

    // q/k nonlinear chains (qe bf16 lives in `out`)
    k_qcol_partial<<<dim3(2, 16, 8), 256, 0, stream>>>(qe, qpart);
    k_qcol_reduce<<<16, 256, 0, stream>>>(qpart, qsum);
    k_qrow<<<8192, 256, 0, stream>>>(qe, qsum, invsc, qb);
    k_krow<<<8192, 256, 0, stream>>>(kb, invsc);
    k_colsum_part<<<dim3(16, 8), 256, 0, stream>>>(kb, kpart);
    k_colsum_red<<<16, 256, 0, stream>>>(kpart, ksum);
    k_z<<<8192, 256, 0, stream>>>(qb, ksum, zbuf);

    // kv^T[b,d,c] = sum_j v[b,j,d] k[b,j,c]  — split-K x4; partials in `out`
    // (qe there is dead after k_qrow; EP_ATTN fully overwrites `out` after)
    gemm_tn_splitk<<<dim3(4, 4, 32), 256, 0, stream>>>(vb, 512, NC, kb, 512, NC, out);
    k_kvred<<<2048, 256, 0, stream>>>(out, kvt);
    // enhanced = shortcut + z*(q@kv)  -> overwrites partials in `out`
    gemm_bt<EP_ATTN><<<dim3(4, 32, 8), 256, 0, stream>>>(qb, 512, NC, kvt, 512, 262144, out, 512, NC, 512, nullptr, x, NC, zbuf, 4096);

    // MixFFN: LN once over all rows, then 4 quarters over dead attn buffers
    k_dwT<<<72, 256, 0, stream>>>(dw_w, dwwT);
    k_ln512<<<8192, 256, 0, stream>>>(out, lnm_g, lnm_b, tbuf);
    for (int q4 = 0; q4 < 4; ++q4) {
        float* outq = out + (long)q4 * 8192 * CDIM;
        bf16* tq = tbuf + (long)q4 * 8192 * CDIM;
        gemm_bt<EP_BF16_BCOL><<<dim3(16, 64, 1), 256, 0, stream>>>(tq, 512, 0, fc1wT, 512, 0, abuf, 2048, 0, 512, fc1_b, nullptr, 0, nullptr, 0);
        k_dwlngelu4<<<2048, 256, 0, stream>>>(abuf, dwwT, dw_b, ln1_g, ln1_b, axbuf);
        gemm_bt<EP_OUT><<<dim3(4, 64, 1), 256, 0, stream>>>(axbuf, 2048, 0, fc2wT, 2048, 0, outq, 512, 0, 2048, fc2_b, outq, 0, nullptr, 0);
    }
}

// Round 6
// 670.204 us; speedup vs baseline: 1.8304x; 1.1071x over previous
//
#include <hip/hip_runtime.h>
#include <hip/hip_bf16.h>

typedef __hip_bfloat16 bf16;
typedef __attribute__((ext_vector_type(8))) short bh8;      // 8 x bf16 bits
typedef __attribute__((ext_vector_type(4))) short bh4;      // 4 x bf16 bits
typedef __attribute__((ext_vector_type(4))) float f32x4;

#define CDIM 512
#define NDIM 4096
#define HIDD 2048
#define BATCH 8

__device__ __forceinline__ float bf2f(short s) {
    union { unsigned u; float f; } c; c.u = ((unsigned)(unsigned short)s) << 16; return c.f;
}
__device__ __forceinline__ short f2bf(float f) {
    union { __hip_bfloat16 h; short s; } c; c.h = __float2bfloat16(f); return c.s;
}
__device__ __forceinline__ float wsum(float v) {
#pragma unroll
    for (int o = 32; o; o >>= 1) v += __shfl_xor(v, o);
    return v;
}
__device__ __forceinline__ float wmax(float v) {
#pragma unroll
    for (int o = 32; o; o >>= 1) v = fmaxf(v, __shfl_xor(v, o));
    return v;
}

#define GLL(g, l) __builtin_amdgcn_global_load_lds( \
    (const __attribute__((address_space(1))) unsigned int*)(g), \
    (__attribute__((address_space(3))) unsigned int*)(l), 16, 0, 0)

// XCD-aware bijective block swizzle (T1): contiguous work-chunk per XCD.
// Requires nwg % 8 == 0 (all our grids satisfy this).
__device__ __forceinline__ void xcd_swz(int& bx, int& by, int& bz) {
    const int gx = gridDim.x, gy = gridDim.y;
    const int nwg = gx * gy * gridDim.z;
    int lid = blockIdx.x + gx * (blockIdx.y + gy * blockIdx.z);
    const int cpx = nwg >> 3;
    int swz = (lid & 7) * cpx + (lid >> 3);
    bx = swz % gx; swz /= gx;
    by = swz % gy;
    bz = swz / gy;
}

// ---------------------------------------------------------------- GEMM (NT)
// C[M,N] = A(M,K) @ Bt(N,K)^T, row-major bf16, fp32 accum. TMx128 tile, BK=64.
// LDS tiles XOR-swizzled (pre-swizzled GLL source + swizzled fragment read):
// chunk' = kchunk ^ (row&7) -> 2 lanes/bank-quad on ds_read_b128 (conflict-free).
enum { EP_QEXP = 0, EP_BF16_BROW = 1, EP_ATTN = 3, EP_BF16_BCOL = 4, EP_OUT = 5 };

template<int MODE, int TM>
__global__ __launch_bounds__(256)
void gemm_bt(const bf16* __restrict__ A, int lda, long sA,
             const bf16* __restrict__ Bt, int ldb, long sB,
             void* __restrict__ Cp, int ldc, long sC, int K,
             const float* __restrict__ bias,
             const float* __restrict__ aux1, long sAux1,
             const float* __restrict__ aux2, long sAux2)
{
    constexpr int MF = TM / 32;                 // A-frags per wave; also A-chunks/thread
    __shared__ __align__(16) bf16 As[TM * 64];
    __shared__ __align__(16) bf16 Bs[128 * 64];
    int bx, by, bz;
    xcd_swz(bx, by, bz);
    const bf16* Ab = A + (long)bz * sA + (long)by * TM * lda;
    const bf16* Bb = Bt + (long)bz * sB + (long)bx * 128 * ldb;
    const int t = threadIdx.x, lane = t & 63, wid = t >> 6;
    const int wm = wid >> 1, wn = wid & 1, lg = lane >> 4, lr = lane & 15;

    f32x4 acc[MF][4];
#pragma unroll
    for (int m = 0; m < MF; ++m)
#pragma unroll
        for (int n = 0; n < 4; ++n) acc[m][n] = (f32x4){0.f, 0.f, 0.f, 0.f};

    for (int kt = 0; kt < K; kt += 64) {
#pragma unroll
        for (int i = 0; i < MF; ++i) {
            const int ch = i * 256 + t;
            const int row = ch >> 3;
            const int cs = (ch & 7) ^ (row & 7);    // pre-swizzled source chunk
            GLL(Ab + (long)row * lda + kt + (cs << 3), (char*)As + i * 4096 + wid * 1024);
        }
#pragma unroll
        for (int i = 0; i < 4; ++i) {
            const int ch = i * 256 + t;
            const int row = ch >> 3;
            const int cs = (ch & 7) ^ (row & 7);
            GLL(Bb + (long)row * ldb + kt + (cs << 3), (char*)Bs + i * 4096 + wid * 1024);
        }
        __syncthreads();
#pragma unroll
        for (int kk = 0; kk < 2; ++kk) {
            bh8 af[MF], bfv[4];
#pragma unroll
            for (int m = 0; m < MF; ++m) {
                const int row = wm * (TM / 2) + m * 16 + lr;
                const int kc = (kk * 4 + lg) ^ (row & 7);
                af[m] = *(const bh8*)(As + row * 64 + kc * 8);
            }
#pragma unroll
            for (int n = 0; n < 4; ++n) {
                const int row = wn * 64 + n * 16 + lr;
                const int kc = (kk * 4 + lg) ^ (row & 7);
                bfv[n] = *(const bh8*)(Bs + row * 64 + kc * 8);
            }
#pragma unroll
            for (int m = 0; m < MF; ++m)
#pragma unroll
                for (int n = 0; n < 4; ++n)
                    acc[m][n] = __builtin_amdgcn_mfma_f32_16x16x32_bf16(af[m], bfv[n], acc[m][n], 0, 0, 0);
        }
        __syncthreads();
    }

    const int gr0 = by * TM + wm * (TM / 2);
    const int gc0 = bx * 128 + wn * 64;
#pragma unroll
    for (int m = 0; m < MF; ++m) {
#pragma unroll
        for (int n = 0; n < 4; ++n) {
            const int gc = gc0 + n * 16 + lr;
#pragma unroll
            for (int r = 0; r < 4; ++r) {
                const int gr = gr0 + m * 16 + lg * 4 + r;
                float v = acc[m][n][r];
                if constexpr (MODE == EP_QEXP) {
                    // conv-q: store exp(raw) as bf16 (consumed by softmax chain)
                    ((bf16*)Cp + (long)bz * sC)[(long)gr * ldc + gc] = __float2bfloat16(expf(v + bias[gr]));
                } else if constexpr (MODE == EP_BF16_BROW) {
                    ((bf16*)Cp + (long)bz * sC)[(long)gr * ldc + gc] = __float2bfloat16(v + bias[gr]);
                } else if constexpr (MODE == EP_ATTN) {
                    const float* xg = aux1 + (long)bz * sAux1;   // x[b] (C, N): shortcut
                    const float* zg = aux2 + (long)bz * sAux2;   // z[b] (N)
                    ((float*)Cp + (long)bz * sC)[(long)gr * ldc + gc] = zg[gr] * v + xg[(long)gc * NDIM + gr];
                } else if constexpr (MODE == EP_BF16_BCOL) {
                    ((bf16*)Cp + (long)bz * sC)[(long)gr * ldc + gc] = __float2bfloat16(v + bias[gc]);
                } else { // EP_OUT: out = acc + bias[col] + out (in-place residual)
                    float* op = (float*)Cp;
                    const long idx = (long)gr * ldc + gc;
                    op[idx] = v + bias[gc] + aux1[idx];
                }
            }
        }
    }
}

// ---------------------------------------------------------------- GEMM (TN, split-K x4)
// part[b,ks] (512x512) = A[b,ks-chunk]^T @ B[b,ks-chunk];  A,B: (4096 x 512) row-major.
// Grid (4, 4, 8*4): z = b*4 + ks, each handles K-chunk of 1024.
// XOR-swizzled staging (source-side) -> conflict-free column-fragment reads.
__global__ __launch_bounds__(256)
void gemm_tn_splitk(const bf16* __restrict__ A, int lda, long sA,
                    const bf16* __restrict__ B, int ldb, long sB,
                    float* __restrict__ part)
{
    __shared__ __align__(16) short As[64 * 128];
    __shared__ __align__(16) short Bs[64 * 128];
    int bx, by, bzl;
    xcd_swz(bx, by, bzl);
    const int bz = bzl >> 2, ks = bzl & 3;
    const bf16* Ab = A + (long)bz * sA + (long)ks * 1024 * lda + by * 128;
    const bf16* Bb = B + (long)bz * sB + (long)ks * 1024 * ldb + bx * 128;
    const int t = threadIdx.x, lane = t & 63, wid = t >> 6;
    const int wm = wid >> 1, wn = wid & 1, lg = lane >> 4, lr = lane & 15;

    f32x4 acc[4][4];
#pragma unroll
    for (int m = 0; m < 4; ++m)
#pragma unroll
        for (int n = 0; n < 4; ++n) acc[m][n] = (f32x4){0.f, 0.f, 0.f, 0.f};

    for (int kt = 0; kt < 1024; kt += 64) {
#pragma unroll
        for (int i = 0; i < 4; ++i) {
            const int ch = i * 256 + t;                 // linear 16B-chunk id
            const int row = ch >> 4;                    // k within tile
            const int cs = (ch & 15) ^ (((row >> 3) & 3) << 1);  // swizzled src chunk
            GLL(Ab + (long)(kt + row) * lda + (cs << 3), (char*)As + i * 4096 + wid * 1024);
            GLL(Bb + (long)(kt + row) * ldb + (cs << 3), (char*)Bs + i * 4096 + wid * 1024);
        }
        __syncthreads();
#pragma unroll
        for (int kk = 0; kk < 2; ++kk) {
            bh8 af[4], bfv[4];
#pragma unroll
            for (int m = 0; m < 4; ++m) {
                const int col = wm * 64 + m * 16 + lr;
#pragma unroll
                for (int u = 0; u < 8; ++u) {
                    const int row = kk * 32 + lg * 8 + u;
                    af[m][u] = As[row * 128 + (((col >> 3) ^ (((row >> 3) & 3) << 1)) << 3) + (col & 7)];
                }
            }
#pragma unroll
            for (int n = 0; n < 4; ++n) {
                const int col = wn * 64 + n * 16 + lr;
#pragma unroll
                for (int u = 0; u < 8; ++u) {
                    const int row = kk * 32 + lg * 8 + u;
                    bfv[n][u] = Bs[row * 128 + (((col >> 3) ^ (((row >> 3) & 3) << 1)) << 3) + (col & 7)];
                }
            }
#pragma unroll
            for (int m = 0; m < 4; ++m)
#pragma unroll
                for (int n = 0; n < 4; ++n)
                    acc[m][n] = __builtin_amdgcn_mfma_f32_16x16x32_bf16(af[m], bfv[n], acc[m][n], 0, 0, 0);
        }
        __syncthreads();
    }

    float* po = part + ((long)bzl << 18);               // 512*512 per (b,ks)
    const int gr0 = by * 128 + wm * 64;
    const int gc0 = bx * 128 + wn * 64;
#pragma unroll
    for (int m = 0; m < 4; ++m)
#pragma unroll
        for (int n = 0; n < 4; ++n) {
            const int gc = gc0 + n * 16 + lr;
#pragma unroll
            for (int r = 0; r < 4; ++r) {
                const int gr = gr0 + m * 16 + lg * 4 + r;
                po[(long)gr * 512 + gc] = acc[m][n][r];
            }
        }
}

// kvt[b] = bf16( sum_ks part[b,ks] )   — 4 elems/thread, vectorized.
__global__ __launch_bounds__(256)
void k_kvred(const float* __restrict__ part, bf16* __restrict__ kvt)
{
    const long e = ((long)blockIdx.x * 256 + threadIdx.x) * 4;
    const int b = (int)(e >> 18);
    const int off = (int)(e & 262143);
    f32x4 s = (f32x4){0.f, 0.f, 0.f, 0.f};
#pragma unroll
    for (int ks = 0; ks < 4; ++ks) {
        f32x4 v = *(const f32x4*)(part + (((long)(b * 4 + ks)) << 18) + off);
        s = s + v;
    }
    bh4 o;
#pragma unroll
    for (int j = 0; j < 4; ++j) o[j] = f2bf(s[j]);
    *(bh4*)(kvt + ((long)b << 18) + off) = o;
}

// ---------------------------------------------------------------- transpose
__global__ __launch_bounds__(256)
void k_transpose(const float* __restrict__ src, bf16* __restrict__ dst,
                 int Rd, int Cd, long sSrc, long sDst)
{
    __shared__ float tile[64][65];
    const float* s = src + (long)blockIdx.z * sSrc;
    bf16* d = dst + (long)blockIdx.z * sDst;
    const int r0 = blockIdx.x * 64, c0 = blockIdx.y * 64;
    const int t = threadIdx.x;
#pragma unroll 4
    for (int i = 0; i < 16; ++i) {
        int idx = i * 256 + t;
        int a = idx >> 6, b = idx & 63;
        tile[a][b] = s[(long)(c0 + a) * Rd + r0 + b];
    }
    __syncthreads();
#pragma unroll 4
    for (int i = 0; i < 16; ++i) {
        int idx = i * 256 + t;
        int a = idx >> 6, b = idx & 63;
        d[(long)(r0 + a) * Cd + c0 + b] = __float2bfloat16(tile[b][a]);
    }
}

__global__ void k_cvt_bf16(const float* __restrict__ in, bf16* __restrict__ out, int n) {
    int i = blockIdx.x * 256 + threadIdx.x;
    if (i < n) out[i] = __float2bfloat16(in[i]);
}

__global__ void k_invsc(const float* __restrict__ scale, float* __restrict__ invsc) {
    int j = threadIdx.x;
    invsc[j] = 1.0f / log1pf(expf(scale[j]));   // 1/softplus(scale)
}

__global__ void k_fill(float* o, int n, float v) {
    int i = blockIdx.x * 256 + threadIdx.x; if (i < n) o[i] = v;
}

// dw weights (2048,1,3,3) -> transposed [9][2048] f32
__global__ void k_dwT(const float* __restrict__ w, float* __restrict__ wT) {
    int i = blockIdx.x * 256 + threadIdx.x;
    if (i < HIDD * 9) {
        int chn = i / 9, kk = i % 9;
        wT[kk * HIDD + chn] = w[i];
    }
}

// ------------------------------------------------- q column-softmax denom
// qe holds bf16 exp(conv_q); column j = stride-CDIM walk of flat buf.
__global__ __launch_bounds__(256)
void k_qcol_partial(const bf16* __restrict__ qe, float* __restrict__ qpart) {
    const int j = blockIdx.x * 256 + threadIdx.x;
    const int ic = blockIdx.y, b = blockIdx.z;     // 16 chunks of 256 rows
    const bf16* p = qe + (long)b * (NDIM * CDIM) + (long)ic * 256 * CDIM + j;
    float s = 0.f;
    for (int i = 0; i < 256; ++i) s += bf2f(*(const short*)(p + (long)i * CDIM));
    qpart[((long)b * 16 + ic) * CDIM + j] = s;
}
__global__ __launch_bounds__(256)
void k_qcol_reduce(const float* __restrict__ qpart, float* __restrict__ qsum) {
    const int idx = blockIdx.x * 256 + threadIdx.x;  // B*C = 4096
    const int b = idx >> 9, j = idx & 511;
    float s = 0.f;
#pragma unroll
    for (int ic = 0; ic < 16; ++ic) s += qpart[((long)b * 16 + ic) * CDIM + j];
    qsum[idx] = s;
}

// q row pass: p=(qe/colsum + 1e-6)/sc, keep ||p||, cube, renorm -> bf16
__global__ __launch_bounds__(256)
void k_qrow(const bf16* __restrict__ qe, const float* __restrict__ qsum,
            const float* __restrict__ invsc, bf16* __restrict__ qb)
{
    const long row = (long)blockIdx.x * 4 + (threadIdx.x >> 6);
    const int lane = threadIdx.x & 63;
    const int b = (int)(row >> 12);
    bh8 ev = *(const bh8*)(qe + row * CDIM + lane * 8);
    const float* qs = qsum + b * CDIM + lane * 8;
    const float* is = invsc + lane * 8;
    f32x4 s0 = *(const f32x4*)qs, s1 = *(const f32x4*)(qs + 4);
    f32x4 i0 = *(const f32x4*)is, i1 = *(const f32x4*)(is + 4);
    float q[8];
#pragma unroll
    for (int k = 0; k < 4; ++k) {
        q[k]     = (bf2f(ev[k]) / s0[k] + 1e-6f) * i0[k];
        q[k + 4] = (bf2f(ev[k + 4]) / s1[k] + 1e-6f) * i1[k];
    }
    float s2 = 0.f, s6 = 0.f, q3[8];
#pragma unroll
    for (int k = 0; k < 8; ++k) { s2 += q[k] * q[k]; float c = q[k] * q[k] * q[k]; q3[k] = c; s6 += c * c; }
    s2 = wsum(s2); s6 = wsum(s6);
    const float sc = sqrtf(s2) / sqrtf(s6);
    bh8 o;
#pragma unroll
    for (int k = 0; k < 8; ++k) o[k] = f2bf(q3[k] * sc);
    *(bh8*)(qb + row * CDIM + lane * 8) = o;
}

// k row pass (IN-PLACE, bf16): row softmax (axis=2), /sc, cube, renorm.
__global__ __launch_bounds__(256)
void k_krow(bf16* __restrict__ kb, const float* __restrict__ invsc)
{
    const long row = (long)blockIdx.x * 4 + (threadIdx.x >> 6);
    const int lane = threadIdx.x & 63;
    bh8 v = *(const bh8*)(kb + row * CDIM + lane * 8);
    const float* is = invsc + lane * 8;
    f32x4 i0 = *(const f32x4*)is, i1 = *(const f32x4*)(is + 4);
    float xv[8];
#pragma unroll
    for (int k = 0; k < 8; ++k) xv[k] = bf2f(v[k]);
    float mx = -1e30f;
#pragma unroll
    for (int k = 0; k < 8; ++k) mx = fmaxf(mx, xv[k]);
    mx = wmax(mx);
    float e[8], se = 0.f;
#pragma unroll
    for (int k = 0; k < 8; ++k) { e[k] = expf(xv[k] - mx); se += e[k]; }
    se = wsum(se);
    const float inv = 1.0f / se;
    float q[8];
#pragma unroll
    for (int k = 0; k < 4; ++k) {
        q[k]     = (e[k] * inv + 1e-6f) * i0[k];
        q[k + 4] = (e[k + 4] * inv + 1e-6f) * i1[k];
    }
    float s2 = 0.f, s6 = 0.f, q3[8];
#pragma unroll
    for (int k = 0; k < 8; ++k) { s2 += q[k] * q[k]; float c = q[k] * q[k] * q[k]; q3[k] = c; s6 += c * c; }
    s2 = wsum(s2); s6 = wsum(s6);
    const float sc = sqrtf(s2) / sqrtf(s6);
    bh8 o;
#pragma unroll
    for (int k = 0; k < 8; ++k) o[k] = f2bf(q3[k] * sc);
    *(bh8*)(kb + row * CDIM + lane * 8) = o;
}

// ksum[b,c] = sum_j kb[b,j,c] : two-stage column sum, 16 chunks of 256 rows.
__global__ __launch_bounds__(256)
void k_colsum_part(const bf16* __restrict__ kb, float* __restrict__ part) {
    const int b = blockIdx.y, jc = blockIdx.x, t = threadIdx.x;
    const bf16* p = kb + (long)b * (NDIM * CDIM) + (long)jc * 256 * CDIM + t * 2;
    float s0 = 0.f, s1 = 0.f;
    for (int j = 0; j < 256; ++j) {
        unsigned u = *(const unsigned*)(p + (long)j * CDIM);
        s0 += bf2f((short)(u & 0xffff));
        s1 += bf2f((short)(u >> 16));
    }
    float* o = part + ((long)b * 16 + jc) * CDIM + t * 2;
    o[0] = s0; o[1] = s1;
}
__global__ __launch_bounds__(256)
void k_colsum_red(const float* __restrict__ part, float* __restrict__ ksum) {
    const int idx = blockIdx.x * 256 + threadIdx.x;  // 4096
    const int b = idx >> 9, c = idx & 511;
    float s = 0.f;
#pragma unroll
    for (int jc = 0; jc < 16; ++jc) s += part[((long)b * 16 + jc) * CDIM + c];
    ksum[idx] = s;
}

// z[b,i] = 1/(q[i,:].ksum[b,:] + 1e-6)
__global__ __launch_bounds__(256)
void k_z(const bf16* __restrict__ qb, const float* __restrict__ ksum, float* __restrict__ z)
{
    const long row = (long)blockIdx.x * 4 + (threadIdx.x >> 6);
    const int lane = threadIdx.x & 63;
    const int b = (int)(row >> 12);
    bh8 q = *(const bh8*)(qb + row * CDIM + lane * 8);
    const float* ks = ksum + (long)b * CDIM + lane * 8;
    f32x4 k0 = *(const f32x4*)ks, k1 = *(const f32x4*)(ks + 4);
    float s = 0.f;
#pragma unroll
    for (int j = 0; j < 4; ++j) { s += bf2f(q[j]) * k0[j]; s += bf2f(q[j + 4]) * k1[j]; }
    s = wsum(s);
    if (lane == 0) z[row] = 1.0f / (s + 1e-6f);
}

// LN over 512 (lnm), fp32 in -> bf16 out. 1 wave/row.
__global__ __launch_bounds__(256)
void k_ln512(const float* __restrict__ src, const float* __restrict__ g,
             const float* __restrict__ bta, bf16* __restrict__ dst)
{
    const long row = (long)blockIdx.x * 4 + (threadIdx.x >> 6);
    const int lane = threadIdx.x & 63;
    const float* p = src + row * CDIM + lane * 8;
    f32x4 a0 = *(const f32x4*)p, a1 = *(const f32x4*)(p + 4);
    float s = 0.f, ss = 0.f;
#pragma unroll
    for (int k = 0; k < 4; ++k) { s += a0[k] + a1[k]; ss += a0[k] * a0[k] + a1[k] * a1[k]; }
    s = wsum(s); ss = wsum(ss);
    const float mean = s * (1.0f / 512), var = ss * (1.0f / 512) - mean * mean;
    const float rstd = rsqrtf(var + 1e-5f);
    const float* gp = g + lane * 8;
    const float* bp = bta + lane * 8;
    f32x4 g0 = *(const f32x4*)gp, g1 = *(const f32x4*)(gp + 4);
    f32x4 b0 = *(const f32x4*)bp, b1 = *(const f32x4*)(bp + 4);
    bh8 o;
#pragma unroll
    for (int k = 0; k < 4; ++k) {
        o[k]     = f2bf((a0[k] - mean) * rstd * g0[k] + b0[k]);
        o[k + 4] = f2bf((a1[k] - mean) * rstd * g1[k] + b1[k]);
    }
    *(bh8*)(dst + row * CDIM + lane * 8) = o;
}

// depthwise 3x3 (SAME) + skip + LN(2048) + exact GELU.
// 4 tokens (same row, 4-aligned) per block; coalesced transposed weights.
__global__ __launch_bounds__(256)
void k_dwlngelu4(const bf16* __restrict__ a, const float* __restrict__ dwwT,
                 const float* __restrict__ dwb, const float* __restrict__ g1,
                 const float* __restrict__ b1, bf16* __restrict__ ax)
{
    const long s0 = (long)blockIdx.x * 4;       // quad-base token (quarter-local)
    const int h = (int)((s0 >> 6) & 63);        // row within image (batch bdry is 64-aligned)
    const int w0 = (int)(s0 & 63);              // 4-aligned column
    const int ch = threadIdx.x * 8;

    float wgt[9][8];
#pragma unroll
    for (int kk = 0; kk < 9; ++kk) {
        f32x4 w0v = *(const f32x4*)(dwwT + kk * HIDD + ch);
        f32x4 w1v = *(const f32x4*)(dwwT + kk * HIDD + ch + 4);
#pragma unroll
        for (int j = 0; j < 4; ++j) { wgt[kk][j] = w0v[j]; wgt[kk][j + 4] = w1v[j]; }
    }
#pragma unroll
    for (int j = 0; j < 8; ++j) wgt[4][j] += 1.0f;   // fold the skip (dw + a)

    float acc[4][8];
    {
        f32x4 d0 = *(const f32x4*)(dwb + ch), d1 = *(const f32x4*)(dwb + ch + 4);
#pragma unroll
        for (int ti = 0; ti < 4; ++ti)
#pragma unroll
            for (int j = 0; j < 4; ++j) { acc[ti][j] = d0[j]; acc[ti][j + 4] = d1[j]; }
    }

#pragma unroll
    for (int dy = -1; dy <= 1; ++dy) {
        const int hh = h + dy;
        if ((unsigned)hh >= 64u) continue;       // wave-uniform
#pragma unroll
        for (int c = -1; c <= 4; ++c) {
            const int ww = w0 + c;
            if ((unsigned)ww >= 64u) continue;   // wave-uniform
            bh8 v = *(const bh8*)(a + (s0 + (long)dy * 64 + c) * HIDD + ch);
            float f[8];
#pragma unroll
            for (int j = 0; j < 8; ++j) f[j] = bf2f(v[j]);
#pragma unroll
            for (int ti = 0; ti < 4; ++ti) {
                const int dx = c - ti;
                if (dx < -1 || dx > 1) continue;
                const int kk = (dy + 1) * 3 + (dx + 1);
#pragma unroll
                for (int j = 0; j < 8; ++j) acc[ti][j] += wgt[kk][j] * f[j];
            }
        }
    }

    // LN(2048) per token
    float sv[4], qv[4];
#pragma unroll
    for (int ti = 0; ti < 4; ++ti) {
        float s = 0.f, q = 0.f;
#pragma unroll
        for (int j = 0; j < 8; ++j) { s += acc[ti][j]; q += acc[ti][j] * acc[ti][j]; }
        sv[ti] = wsum(s); qv[ti] = wsum(q);
    }
    __shared__ float red[4][4][2];
    const int wid = threadIdx.x >> 6, lane = threadIdx.x & 63;
    if (lane == 0)
#pragma unroll
        for (int ti = 0; ti < 4; ++ti) { red[wid][ti][0] = sv[ti]; red[wid][ti][1] = qv[ti]; }
    __syncthreads();

    f32x4 ga = *(const f32x4*)(g1 + ch), gb = *(const f32x4*)(g1 + ch + 4);
    f32x4 ba = *(const f32x4*)(b1 + ch), bb = *(const f32x4*)(b1 + ch + 4);
    float gg[8], bb8[8];
#pragma unroll
    for (int j = 0; j < 4; ++j) { gg[j] = ga[j]; gg[j + 4] = gb[j]; bb8[j] = ba[j]; bb8[j + 4] = bb[j]; }

#pragma unroll
    for (int ti = 0; ti < 4; ++ti) {
        const float s = red[0][ti][0] + red[1][ti][0] + red[2][ti][0] + red[3][ti][0];
        const float q = red[0][ti][1] + red[1][ti][1] + red[2][ti][1] + red[3][ti][1];
        const float mean = s * (1.0f / 2048), var = q * (1.0f / 2048) - mean * mean;
        const float rstd = rsqrtf(var + 1e-5f);
        bh8 o;
#pragma unroll
        for (int j = 0; j < 8; ++j) {
            float y = (acc[ti][j] - mean) * rstd * gg[j] + bb8[j];
            o[j] = f2bf(0.5f * y * (1.0f + erff(y * 0.70710678118654752f)));
        }
        *(bh8*)(ax + (s0 + ti) * HIDD + ch) = o;
    }
}

// ---------------------------------------------------------------- launch
extern "C" void kernel_launch(void* const* d_in, const int* in_sizes, int n_in,
                              void* d_out, int out_size, void* d_ws, size_t ws_size,
                              hipStream_t stream) {
    const float* x     = (const float*)d_in[0];
    const float* Wq    = (const float*)d_in[1];
    const float* bq    = (const float*)d_in[2];
    const float* Wk    = (const float*)d_in[3];
    const float* bk    = (const float*)d_in[4];
    const float* Wv    = (const float*)d_in[5];
    const float* bv    = (const float*)d_in[6];
    const float* scale = (const float*)d_in[7];
    const float* fc1_w = (const float*)d_in[8];
    const float* fc1_b = (const float*)d_in[9];
    const float* dw_w  = (const float*)d_in[10];
    const float* dw_b  = (const float*)d_in[11];
    const float* fc2_w = (const float*)d_in[12];
    const float* fc2_b = (const float*)d_in[13];
    const float* ln1_g = (const float*)d_in[14];
    const float* ln1_b = (const float*)d_in[15];
    const float* lnm_g = (const float*)d_in[16];
    const float* lnm_b = (const float*)d_in[17];
    float* out = (float*)d_out;
    char* p = (char*)d_ws;

    // ---- workspace layout (qe / kv-partials / enhanced live in d_out) ----
    bf16*  xbT   = (bf16*)(p + 0);            // 32 MiB: x^T  -> later qb
    bf16*  kb    = (bf16*)(p + 33554432);     // 32 MiB: conv-k (bf16), softmax in-place
    bf16*  vb    = (bf16*)(p + 67108864);     // 32 MiB: conv-v -> later tbuf (full)
    bf16*  kvt   = (bf16*)(p + 100663296);    //  4 MiB: kv^T (B,512,512)
    bf16*  wqb   = (bf16*)(p + 104857600);
    bf16*  wkb   = (bf16*)(p + 105381888);
    bf16*  wvb   = (bf16*)(p + 105906176);
    bf16*  fc1wT = (bf16*)(p + 106430464);    //  2 MiB
    bf16*  fc2wT = (bf16*)(p + 108527616);    //  2 MiB
    float* invsc = (float*)(p + 110624768);
    float* dwwT  = (float*)(p + 110626816);   // 73,728 B
    float* qsum  = (float*)(p + 110757888);
    float* kpartX= (float*)(p + 110774272);   // (unused; layout clarity)
    float* ksum  = (float*)(p + 110905344);
    float* zbuf  = (float*)(p + 110921728);
    const size_t REQUIRED = 111052800;
    // overlays: qpart/kpart live in the kvt region (dead until kv GEMM)
    float* qpart = (float*)kvt;               // 8*16*512*4 = 262,144 B
    float* kpart = (float*)((char*)kvt + 262144);   // 262,144 B
    // qe: bf16 exp(conv_q) lives in d_out (dead before EP_ATTN overwrites)
    bf16*  qe    = (bf16*)out;                // 64 MiB
    // FFN-phase overlays:
    bf16*  qb    = xbT;                       // after convs, xbT dead
    bf16*  abuf  = (bf16*)(p + 0);            // after attn, qb dead (32 MiB)
    bf16*  axbuf = (bf16*)(p + 33554432);     // kb dead (32 MiB)
    bf16*  tbuf  = (bf16*)(p + 67108864);     // vb dead (32 MiB, full-batch LN out)

    if (ws_size < REQUIRED) {   // sentinel encodes actual ws size in MiB
        k_fill<<<(out_size + 255) / 256, 256, 0, stream>>>(out, out_size, 100000.0f + (float)(ws_size >> 20));
        return;
    }
    (void)kpartX;

    const long NC = (long)NDIM * CDIM;  // 2,097,152 elements per batch

    // pack / convert params
    k_cvt_bf16<<<1024, 256, 0, stream>>>(Wq, wqb, 262144);
    k_cvt_bf16<<<1024, 256, 0, stream>>>(Wk, wkb, 262144);
    k_cvt_bf16<<<1024, 256, 0, stream>>>(Wv, wvb, 262144);
    k_transpose<<<dim3(32, 8, 1), 256, 0, stream>>>(fc1_w, fc1wT, 2048, 512, 0, 0);
    k_transpose<<<dim3(8, 32, 1), 256, 0, stream>>>(fc2_w, fc2wT, 512, 2048, 0, 0);
    k_invsc<<<1, 512, 0, stream>>>(scale, invsc);
    k_transpose<<<dim3(64, 8, BATCH), 256, 0, stream>>>(x, xbT, 4096, 512, NC, NC);

    // conv1x1 GEMMs: out[b](C=512, s=4096) = W @ x[b]; flat == raw (B,N,C) view
    gemm_bt<EP_QEXP, 128><<<dim3(32, 4, 8), 256, 0, stream>>>(wqb, 512, 0, xbT, 512, NC, qe, 4096, NC, 512, bq, nullptr, 0, nullptr, 0);
    gemm_bt<EP_BF16_BROW, 128><<<dim3(32, 4, 8), 256, 0, stream>>>(wkb, 512, 0, xbT, 512, NC, kb, 4096, NC, 512, bk, nullptr, 0, nullptr, 0);
    gemm_bt<EP_BF16_BROW, 128><<<dim3(32, 4, 8), 256, 0, stream>>>(wvb, 512, 0, xbT, 512, NC, vb, 4096, NC, 512, bv, nullptr, 0, nullptr, 0);

    // q/k nonlinear chains (qe bf16 lives in `out`)
    k_qcol_partial<<<dim3(2, 16, 8), 256, 0, stream>>>(qe, qpart);
    k_qcol_reduce<<<16, 256, 0, stream>>>(qpart, qsum);
    k_qrow<<<8192, 256, 0, stream>>>(qe, qsum, invsc, qb);
    k_krow<<<8192, 256, 0, stream>>>(kb, invsc);
    k_colsum_part<<<dim3(16, 8), 256, 0, stream>>>(kb, kpart);
    k_colsum_red<<<16, 256, 0, stream>>>(kpart, ksum);
    k_z<<<8192, 256, 0, stream>>>(qb, ksum, zbuf);

    // kv^T[b,d,c] = sum_j v[b,j,d] k[b,j,c]  — split-K x4; partials in `out`
    gemm_tn_splitk<<<dim3(4, 4, 32), 256, 0, stream>>>(vb, 512, NC, kb, 512, NC, out);
    k_kvred<<<2048, 256, 0, stream>>>(out, kvt);
    // enhanced = shortcut + z*(q@kv)  -> overwrites partials in `out`
    gemm_bt<EP_ATTN, 128><<<dim3(4, 32, 8), 256, 0, stream>>>(qb, 512, NC, kvt, 512, 262144, out, 512, NC, 512, nullptr, x, NC, zbuf, 4096);

    // MixFFN: LN once over all rows, then 4 quarters over dead attn buffers
    k_dwT<<<72, 256, 0, stream>>>(dw_w, dwwT);
    k_ln512<<<8192, 256, 0, stream>>>(out, lnm_g, lnm_b, tbuf);
    for (int q4 = 0; q4 < 4; ++q4) {
        float* outq = out + (long)q4 * 8192 * CDIM;
        bf16* tq = tbuf + (long)q4 * 8192 * CDIM;
        gemm_bt<EP_BF16_BCOL, 128><<<dim3(16, 64, 1), 256, 0, stream>>>(tq, 512, 0, fc1wT, 512, 0, abuf, 2048, 0, 512, fc1_b, nullptr, 0, nullptr, 0);
        k_dwlngelu4<<<2048, 256, 0, stream>>>(abuf, dwwT, dw_b, ln1_g, ln1_b, axbuf);
        // fc2: 64x128 tile -> 512 blocks (2/CU) to restore co-resident overlap
        gemm_bt<EP_OUT, 64><<<dim3(4, 128, 1), 256, 0, stream>>>(axbuf, 2048, 0, fc2wT, 2048, 0, outq, 512, 0, 2048, fc2_b, outq, 0, nullptr, 0);
    }
}

// Round 7
// 640.380 us; speedup vs baseline: 1.9157x; 1.0466x over previous
//
#include <hip/hip_runtime.h>
#include <hip/hip_bf16.h>

typedef __hip_bfloat16 bf16;
typedef __attribute__((ext_vector_type(8))) short bh8;      // 8 x bf16 bits
typedef __attribute__((ext_vector_type(4))) short bh4;      // 4 x bf16 bits
typedef __attribute__((ext_vector_type(4))) float f32x4;

#define CDIM 512
#define NDIM 4096
#define HIDD 2048
#define BATCH 8

__device__ __forceinline__ float bf2f(short s) {
    union { unsigned u; float f; } c; c.u = ((unsigned)(unsigned short)s) << 16; return c.f;
}
__device__ __forceinline__ short f2bf(float f) {
    union { __hip_bfloat16 h; short s; } c; c.h = __float2bfloat16(f); return c.s;
}
__device__ __forceinline__ float wsum(float v) {
#pragma unroll
    for (int o = 32; o; o >>= 1) v += __shfl_xor(v, o);
    return v;
}
__device__ __forceinline__ float wmax(float v) {
#pragma unroll
    for (int o = 32; o; o >>= 1) v = fmaxf(v, __shfl_xor(v, o));
    return v;
}

#define GLL(g, l) __builtin_amdgcn_global_load_lds( \
    (const __attribute__((address_space(1))) unsigned int*)(g), \
    (__attribute__((address_space(3))) unsigned int*)(l), 16, 0, 0)

// XCD-aware bijective block swizzle (T1): contiguous work-chunk per XCD.
// Requires nwg % 8 == 0 (all our grids satisfy this).
__device__ __forceinline__ void xcd_swz(int& bx, int& by, int& bz) {
    const int gx = gridDim.x, gy = gridDim.y;
    const int nwg = gx * gy * gridDim.z;
    int lid = blockIdx.x + gx * (blockIdx.y + gy * blockIdx.z);
    const int cpx = nwg >> 3;
    int swz = (lid & 7) * cpx + (lid >> 3);
    bx = swz % gx; swz /= gx;
    by = swz % gy;
    bz = swz / gy;
}

// ---------------------------------------------------------------- GEMM (NT)
// C[M,N] = A(M,K) @ Bt(N,K)^T, row-major bf16, fp32 accum. TMx128 tile, BK=64.
// LDS tiles XOR-swizzled (pre-swizzled GLL source + swizzled fragment read).
enum { EP_QEXP = 0, EP_BF16_BROW = 1, EP_ATTN = 3, EP_BF16_BCOL = 4, EP_OUT = 5 };

template<int MODE, int TM>
__global__ __launch_bounds__(256)
void gemm_bt(const bf16* __restrict__ A, int lda, long sA,
             const bf16* __restrict__ Bt, int ldb, long sB,
             void* __restrict__ Cp, int ldc, long sC, int K,
             const float* __restrict__ bias,
             const void* __restrict__ aux1, long sAux1,
             const float* __restrict__ aux2, long sAux2)
{
    constexpr int MF = TM / 32;                 // A-frags per wave; also A-chunks/thread
    __shared__ __align__(16) bf16 As[TM * 64];
    __shared__ __align__(16) bf16 Bs[128 * 64];
    int bx, by, bz;
    xcd_swz(bx, by, bz);
    const bf16* Ab = A + (long)bz * sA + (long)by * TM * lda;
    const bf16* Bb = Bt + (long)bz * sB + (long)bx * 128 * ldb;
    const int t = threadIdx.x, lane = t & 63, wid = t >> 6;
    const int wm = wid >> 1, wn = wid & 1, lg = lane >> 4, lr = lane & 15;

    f32x4 acc[MF][4];
#pragma unroll
    for (int m = 0; m < MF; ++m)
#pragma unroll
        for (int n = 0; n < 4; ++n) acc[m][n] = (f32x4){0.f, 0.f, 0.f, 0.f};

    for (int kt = 0; kt < K; kt += 64) {
#pragma unroll
        for (int i = 0; i < MF; ++i) {
            const int ch = i * 256 + t;
            const int row = ch >> 3;
            const int cs = (ch & 7) ^ (row & 7);    // pre-swizzled source chunk
            GLL(Ab + (long)row * lda + kt + (cs << 3), (char*)As + i * 4096 + wid * 1024);
        }
#pragma unroll
        for (int i = 0; i < 4; ++i) {
            const int ch = i * 256 + t;
            const int row = ch >> 3;
            const int cs = (ch & 7) ^ (row & 7);
            GLL(Bb + (long)row * ldb + kt + (cs << 3), (char*)Bs + i * 4096 + wid * 1024);
        }
        __syncthreads();
#pragma unroll
        for (int kk = 0; kk < 2; ++kk) {
            bh8 af[MF], bfv[4];
#pragma unroll
            for (int m = 0; m < MF; ++m) {
                const int row = wm * (TM / 2) + m * 16 + lr;
                const int kc = (kk * 4 + lg) ^ (row & 7);
                af[m] = *(const bh8*)(As + row * 64 + kc * 8);
            }
#pragma unroll
            for (int n = 0; n < 4; ++n) {
                const int row = wn * 64 + n * 16 + lr;
                const int kc = (kk * 4 + lg) ^ (row & 7);
                bfv[n] = *(const bh8*)(Bs + row * 64 + kc * 8);
            }
#pragma unroll
            for (int m = 0; m < MF; ++m)
#pragma unroll
                for (int n = 0; n < 4; ++n)
                    acc[m][n] = __builtin_amdgcn_mfma_f32_16x16x32_bf16(af[m], bfv[n], acc[m][n], 0, 0, 0);
        }
        __syncthreads();
    }

    const int gr0 = by * TM + wm * (TM / 2);
    const int gc0 = bx * 128 + wn * 64;
#pragma unroll
    for (int m = 0; m < MF; ++m) {
#pragma unroll
        for (int n = 0; n < 4; ++n) {
            const int gc = gc0 + n * 16 + lr;
#pragma unroll
            for (int r = 0; r < 4; ++r) {
                const int gr = gr0 + m * 16 + lg * 4 + r;
                float v = acc[m][n][r];
                if constexpr (MODE == EP_QEXP) {
                    // conv-q: store exp(raw) as bf16 (consumed by softmax chain)
                    ((bf16*)Cp + (long)bz * sC)[(long)gr * ldc + gc] = __float2bfloat16(expf(v + bias[gr]));
                } else if constexpr (MODE == EP_BF16_BROW) {
                    ((bf16*)Cp + (long)bz * sC)[(long)gr * ldc + gc] = __float2bfloat16(v + bias[gr]);
                } else if constexpr (MODE == EP_ATTN) {
                    // shortcut from xbT (bf16, (N,C) row-major -> coalesced)
                    const bf16* xg = (const bf16*)aux1 + (long)bz * sAux1;
                    const float* zg = aux2 + (long)bz * sAux2;   // z[b] (N)
                    ((float*)Cp + (long)bz * sC)[(long)gr * ldc + gc] =
                        zg[gr] * v + bf2f(*(const short*)(xg + (long)gr * 512 + gc));
                } else if constexpr (MODE == EP_BF16_BCOL) {
                    ((bf16*)Cp + (long)bz * sC)[(long)gr * ldc + gc] = __float2bfloat16(v + bias[gc]);
                } else { // EP_OUT: out = acc + bias[col] + out (in-place residual)
                    float* op = (float*)Cp;
                    const long idx = (long)gr * ldc + gc;
                    op[idx] = v + bias[gc] + ((const float*)aux1)[idx];
                }
            }
        }
    }
}

// ---------------------------------------------------------------- GEMM (TN, split-K x4)
// part[b,ks] (512x512 bf16) = A[b,ks-chunk]^T @ B[b,ks-chunk]; A,B: (4096x512) row-major.
// Grid (4, 4, 8*4): z = b*4 + ks, each handles K-chunk of 1024.
__global__ __launch_bounds__(256)
void gemm_tn_splitk(const bf16* __restrict__ A, int lda, long sA,
                    const bf16* __restrict__ B, int ldb, long sB,
                    bf16* __restrict__ part)
{
    __shared__ __align__(16) short As[64 * 128];
    __shared__ __align__(16) short Bs[64 * 128];
    int bx, by, bzl;
    xcd_swz(bx, by, bzl);
    const int bz = bzl >> 2, ks = bzl & 3;
    const bf16* Ab = A + (long)bz * sA + (long)ks * 1024 * lda + by * 128;
    const bf16* Bb = B + (long)bz * sB + (long)ks * 1024 * ldb + bx * 128;
    const int t = threadIdx.x, lane = t & 63, wid = t >> 6;
    const int wm = wid >> 1, wn = wid & 1, lg = lane >> 4, lr = lane & 15;

    f32x4 acc[4][4];
#pragma unroll
    for (int m = 0; m < 4; ++m)
#pragma unroll
        for (int n = 0; n < 4; ++n) acc[m][n] = (f32x4){0.f, 0.f, 0.f, 0.f};

    for (int kt = 0; kt < 1024; kt += 64) {
#pragma unroll
        for (int i = 0; i < 4; ++i) {
            const int ch = i * 256 + t;                 // linear 16B-chunk id
            const int row = ch >> 4;                    // k within tile
            const int cs = (ch & 15) ^ (((row >> 3) & 3) << 1);  // swizzled src chunk
            GLL(Ab + (long)(kt + row) * lda + (cs << 3), (char*)As + i * 4096 + wid * 1024);
            GLL(Bb + (long)(kt + row) * ldb + (cs << 3), (char*)Bs + i * 4096 + wid * 1024);
        }
        __syncthreads();
#pragma unroll
        for (int kk = 0; kk < 2; ++kk) {
            bh8 af[4], bfv[4];
#pragma unroll
            for (int m = 0; m < 4; ++m) {
                const int col = wm * 64 + m * 16 + lr;
#pragma unroll
                for (int u = 0; u < 8; ++u) {
                    const int row = kk * 32 + lg * 8 + u;
                    af[m][u] = As[row * 128 + (((col >> 3) ^ (((row >> 3) & 3) << 1)) << 3) + (col & 7)];
                }
            }
#pragma unroll
            for (int n = 0; n < 4; ++n) {
                const int col = wn * 64 + n * 16 + lr;
#pragma unroll
                for (int u = 0; u < 8; ++u) {
                    const int row = kk * 32 + lg * 8 + u;
                    bfv[n][u] = Bs[row * 128 + (((col >> 3) ^ (((row >> 3) & 3) << 1)) << 3) + (col & 7)];
                }
            }
#pragma unroll
            for (int m = 0; m < 4; ++m)
#pragma unroll
                for (int n = 0; n < 4; ++n)
                    acc[m][n] = __builtin_amdgcn_mfma_f32_16x16x32_bf16(af[m], bfv[n], acc[m][n], 0, 0, 0);
        }
        __syncthreads();
    }

    bf16* po = part + ((long)bzl << 18);                // 512*512 per (b,ks)
    const int gr0 = by * 128 + wm * 64;
    const int gc0 = bx * 128 + wn * 64;
#pragma unroll
    for (int m = 0; m < 4; ++m)
#pragma unroll
        for (int n = 0; n < 4; ++n) {
            const int gc = gc0 + n * 16 + lr;
#pragma unroll
            for (int r = 0; r < 4; ++r) {
                const int gr = gr0 + m * 16 + lg * 4 + r;
                po[(long)gr * 512 + gc] = __float2bfloat16(acc[m][n][r]);
            }
        }
}

// kvt[b] = bf16( sum_ks part[b,ks] )   — 8 elems/thread, vectorized.
__global__ __launch_bounds__(256)
void k_kvred(const bf16* __restrict__ part, bf16* __restrict__ kvt)
{
    const long e = ((long)blockIdx.x * 256 + threadIdx.x) * 8;
    const int b = (int)(e >> 18);
    const int off = (int)(e & 262143);
    float s[8] = {0.f, 0.f, 0.f, 0.f, 0.f, 0.f, 0.f, 0.f};
#pragma unroll
    for (int ks = 0; ks < 4; ++ks) {
        bh8 v = *(const bh8*)(part + (((long)(b * 4 + ks)) << 18) + off);
#pragma unroll
        for (int j = 0; j < 8; ++j) s[j] += bf2f(v[j]);
    }
    bh8 o;
#pragma unroll
    for (int j = 0; j < 8; ++j) o[j] = f2bf(s[j]);
    *(bh8*)(kvt + ((long)b << 18) + off) = o;
}

// ---------------------------------------------------------------- transpose
__global__ __launch_bounds__(256)
void k_transpose(const float* __restrict__ src, bf16* __restrict__ dst,
                 int Rd, int Cd, long sSrc, long sDst)
{
    __shared__ float tile[64][65];
    const float* s = src + (long)blockIdx.z * sSrc;
    bf16* d = dst + (long)blockIdx.z * sDst;
    const int r0 = blockIdx.x * 64, c0 = blockIdx.y * 64;
    const int t = threadIdx.x;
#pragma unroll 4
    for (int i = 0; i < 16; ++i) {
        int idx = i * 256 + t;
        int a = idx >> 6, b = idx & 63;
        tile[a][b] = s[(long)(c0 + a) * Rd + r0 + b];
    }
    __syncthreads();
#pragma unroll 4
    for (int i = 0; i < 16; ++i) {
        int idx = i * 256 + t;
        int a = idx >> 6, b = idx & 63;
        d[(long)(r0 + a) * Cd + c0 + b] = __float2bfloat16(tile[b][a]);
    }
}

// convert the three 512x512 conv weights in one pass
__global__ void k_cvt3(const float* __restrict__ a, const float* __restrict__ b,
                       const float* __restrict__ c, bf16* __restrict__ oa,
                       bf16* __restrict__ ob, bf16* __restrict__ oc) {
    int i = blockIdx.x * 256 + threadIdx.x;
    if (i < 262144) {
        oa[i] = __float2bfloat16(a[i]);
        ob[i] = __float2bfloat16(b[i]);
        oc[i] = __float2bfloat16(c[i]);
    }
}

// invsc (512) + dw-weight transpose (2048x9 -> 9x2048) in one launch
__global__ void k_prep(const float* __restrict__ scale, float* __restrict__ invsc,
                       const float* __restrict__ w, float* __restrict__ wT) {
    int i = blockIdx.x * 256 + threadIdx.x;
    if (i < 512) invsc[i] = 1.0f / log1pf(expf(scale[i]));
    if (i < HIDD * 9) {
        int chn = i / 9, kk = i % 9;
        wT[kk * HIDD + chn] = w[i];
    }
}

__global__ void k_fill(float* o, int n, float v) {
    int i = blockIdx.x * 256 + threadIdx.x; if (i < n) o[i] = v;
}

// ------------------------------------------------- q column-softmax denom
// qe holds bf16 exp(conv_q); column j = stride-CDIM walk of flat buf.
__global__ __launch_bounds__(256)
void k_qcol_partial(const bf16* __restrict__ qe, float* __restrict__ qpart) {
    const int j = blockIdx.x * 256 + threadIdx.x;
    const int ic = blockIdx.y, b = blockIdx.z;     // 16 chunks of 256 rows
    const bf16* p = qe + (long)b * (NDIM * CDIM) + (long)ic * 256 * CDIM + j;
    float s = 0.f;
    for (int i = 0; i < 256; ++i) s += bf2f(*(const short*)(p + (long)i * CDIM));
    qpart[((long)b * 16 + ic) * CDIM + j] = s;
}

// combined second-stage reduce: qsum (idx<4096) and ksum (idx>=4096)
__global__ __launch_bounds__(256)
void k_red2(const float* __restrict__ qpart, float* __restrict__ qsum,
            const float* __restrict__ kpart, float* __restrict__ ksum) {
    const int idx = blockIdx.x * 256 + threadIdx.x;  // 8192
    const int which = idx >> 12, r = idx & 4095;
    const int b = r >> 9, c = r & 511;
    const float* src = which ? kpart : qpart;
    float s = 0.f;
#pragma unroll
    for (int jc = 0; jc < 16; ++jc) s += src[((long)(b * 16 + jc)) * CDIM + c];
    (which ? ksum : qsum)[r] = s;
}

// q row pass + fused z: p=(qe/colsum + 1e-6)/sc, ||p||-keep, cube, renorm -> bf16
// then z[row] = 1/(qb . ksum + 1e-6) using the bf16-rounded qb (identical to old k_z)
__global__ __launch_bounds__(256)
void k_qrow(const bf16* __restrict__ qe, const float* __restrict__ qsum,
            const float* __restrict__ invsc, bf16* __restrict__ qb,
            const float* __restrict__ ksum, float* __restrict__ z)
{
    const long row = (long)blockIdx.x * 4 + (threadIdx.x >> 6);
    const int lane = threadIdx.x & 63;
    const int b = (int)(row >> 12);
    bh8 ev = *(const bh8*)(qe + row * CDIM + lane * 8);
    const float* qs = qsum + b * CDIM + lane * 8;
    const float* is = invsc + lane * 8;
    f32x4 s0 = *(const f32x4*)qs, s1 = *(const f32x4*)(qs + 4);
    f32x4 i0 = *(const f32x4*)is, i1 = *(const f32x4*)(is + 4);
    float q[8];
#pragma unroll
    for (int k = 0; k < 4; ++k) {
        q[k]     = (bf2f(ev[k]) / s0[k] + 1e-6f) * i0[k];
        q[k + 4] = (bf2f(ev[k + 4]) / s1[k] + 1e-6f) * i1[k];
    }
    float s2 = 0.f, s6 = 0.f, q3[8];
#pragma unroll
    for (int k = 0; k < 8; ++k) { s2 += q[k] * q[k]; float c = q[k] * q[k] * q[k]; q3[k] = c; s6 += c * c; }
    s2 = wsum(s2); s6 = wsum(s6);
    const float sc = sqrtf(s2) / sqrtf(s6);
    bh8 o;
#pragma unroll
    for (int k = 0; k < 8; ++k) o[k] = f2bf(q3[k] * sc);
    *(bh8*)(qb + row * CDIM + lane * 8) = o;
    // fused z
    const float* ks = ksum + (long)b * CDIM + lane * 8;
    f32x4 k0 = *(const f32x4*)ks, k1 = *(const f32x4*)(ks + 4);
    float zd = 0.f;
#pragma unroll
    for (int j = 0; j < 4; ++j) { zd += bf2f(o[j]) * k0[j]; zd += bf2f(o[j + 4]) * k1[j]; }
    zd = wsum(zd);
    if (lane == 0) z[row] = 1.0f / (zd + 1e-6f);
}

// k row pass (IN-PLACE, bf16): row softmax (axis=2), /sc, cube, renorm.
__global__ __launch_bounds__(256)
void k_krow(bf16* __restrict__ kb, const float* __restrict__ invsc)
{
    const long row = (long)blockIdx.x * 4 + (threadIdx.x >> 6);
    const int lane = threadIdx.x & 63;
    bh8 v = *(const bh8*)(kb + row * CDIM + lane * 8);
    const float* is = invsc + lane * 8;
    f32x4 i0 = *(const f32x4*)is, i1 = *(const f32x4*)(is + 4);
    float xv[8];
#pragma unroll
    for (int k = 0; k < 8; ++k) xv[k] = bf2f(v[k]);
    float mx = -1e30f;
#pragma unroll
    for (int k = 0; k < 8; ++k) mx = fmaxf(mx, xv[k]);
    mx = wmax(mx);
    float e[8], se = 0.f;
#pragma unroll
    for (int k = 0; k < 8; ++k) { e[k] = expf(xv[k] - mx); se += e[k]; }
    se = wsum(se);
    const float inv = 1.0f / se;
    float q[8];
#pragma unroll
    for (int k = 0; k < 4; ++k) {
        q[k]     = (e[k] * inv + 1e-6f) * i0[k];
        q[k + 4] = (e[k + 4] * inv + 1e-6f) * i1[k];
    }
    float s2 = 0.f, s6 = 0.f, q3[8];
#pragma unroll
    for (int k = 0; k < 8; ++k) { s2 += q[k] * q[k]; float c = q[k] * q[k] * q[k]; q3[k] = c; s6 += c * c; }
    s2 = wsum(s2); s6 = wsum(s6);
    const float sc = sqrtf(s2) / sqrtf(s6);
    bh8 o;
#pragma unroll
    for (int k = 0; k < 8; ++k) o[k] = f2bf(q3[k] * sc);
    *(bh8*)(kb + row * CDIM + lane * 8) = o;
}

// ksum partials: column sum of (N,C) rows, 16 chunks of 256 rows.
__global__ __launch_bounds__(256)
void k_colsum_part(const bf16* __restrict__ kb, float* __restrict__ part) {
    const int b = blockIdx.y, jc = blockIdx.x, t = threadIdx.x;
    const bf16* p = kb + (long)b * (NDIM * CDIM) + (long)jc * 256 * CDIM + t * 2;
    float s0 = 0.f, s1 = 0.f;
    for (int j = 0; j < 256; ++j) {
        unsigned u = *(const unsigned*)(p + (long)j * CDIM);
        s0 += bf2f((short)(u & 0xffff));
        s1 += bf2f((short)(u >> 16));
    }
    float* o = part + ((long)b * 16 + jc) * CDIM + t * 2;
    o[0] = s0; o[1] = s1;
}

// LN over 512 (lnm), fp32 in -> bf16 out. 1 wave/row.
__global__ __launch_bounds__(256)
void k_ln512(const float* __restrict__ src, const float* __restrict__ g,
             const float* __restrict__ bta, bf16* __restrict__ dst)
{
    const long row = (long)blockIdx.x * 4 + (threadIdx.x >> 6);
    const int lane = threadIdx.x & 63;
    const float* p = src + row * CDIM + lane * 8;
    f32x4 a0 = *(const f32x4*)p, a1 = *(const f32x4*)(p + 4);
    float s = 0.f, ss = 0.f;
#pragma unroll
    for (int k = 0; k < 4; ++k) { s += a0[k] + a1[k]; ss += a0[k] * a0[k] + a1[k] * a1[k]; }
    s = wsum(s); ss = wsum(ss);
    const float mean = s * (1.0f / 512), var = ss * (1.0f / 512) - mean * mean;
    const float rstd = rsqrtf(var + 1e-5f);
    const float* gp = g + lane * 8;
    const float* bp = bta + lane * 8;
    f32x4 g0 = *(const f32x4*)gp, g1 = *(const f32x4*)(gp + 4);
    f32x4 b0 = *(const f32x4*)bp, b1 = *(const f32x4*)(bp + 4);
    bh8 o;
#pragma unroll
    for (int k = 0; k < 4; ++k) {
        o[k]     = f2bf((a0[k] - mean) * rstd * g0[k] + b0[k]);
        o[k + 4] = f2bf((a1[k] - mean) * rstd * g1[k] + b1[k]);
    }
    *(bh8*)(dst + row * CDIM + lane * 8) = o;
}

// depthwise 3x3 (SAME) + skip + LN(2048) + exact GELU.
// 4 tokens (same row, 4-aligned) per block; coalesced transposed weights.
__global__ __launch_bounds__(256)
void k_dwlngelu4(const bf16* __restrict__ a, const float* __restrict__ dwwT,
                 const float* __restrict__ dwb, const float* __restrict__ g1,
                 const float* __restrict__ b1, bf16* __restrict__ ax)
{
    const long s0 = (long)blockIdx.x * 4;       // quad-base token (quarter-local)
    const int h = (int)((s0 >> 6) & 63);        // row within image (batch bdry is 64-aligned)
    const int w0 = (int)(s0 & 63);              // 4-aligned column
    const int ch = threadIdx.x * 8;

    float wgt[9][8];
#pragma unroll
    for (int kk = 0; kk < 9; ++kk) {
        f32x4 w0v = *(const f32x4*)(dwwT + kk * HIDD + ch);
        f32x4 w1v = *(const f32x4*)(dwwT + kk * HIDD + ch + 4);
#pragma unroll
        for (int j = 0; j < 4; ++j) { wgt[kk][j] = w0v[j]; wgt[kk][j + 4] = w1v[j]; }
    }
#pragma unroll
    for (int j = 0; j < 8; ++j) wgt[4][j] += 1.0f;   // fold the skip (dw + a)

    float acc[4][8];
    {
        f32x4 d0 = *(const f32x4*)(dwb + ch), d1 = *(const f32x4*)(dwb + ch + 4);
#pragma unroll
        for (int ti = 0; ti < 4; ++ti)
#pragma unroll
            for (int j = 0; j < 4; ++j) { acc[ti][j] = d0[j]; acc[ti][j + 4] = d1[j]; }
    }

#pragma unroll
    for (int dy = -1; dy <= 1; ++dy) {
        const int hh = h + dy;
        if ((unsigned)hh >= 64u) continue;       // wave-uniform
#pragma unroll
        for (int c = -1; c <= 4; ++c) {
            const int ww = w0 + c;
            if ((unsigned)ww >= 64u) continue;   // wave-uniform
            bh8 v = *(const bh8*)(a + (s0 + (long)dy * 64 + c) * HIDD + ch);
            float f[8];
#pragma unroll
            for (int j = 0; j < 8; ++j) f[j] = bf2f(v[j]);
#pragma unroll
            for (int ti = 0; ti < 4; ++ti) {
                const int dx = c - ti;
                if (dx < -1 || dx > 1) continue;
                const int kk = (dy + 1) * 3 + (dx + 1);
#pragma unroll
                for (int j = 0; j < 8; ++j) acc[ti][j] += wgt[kk][j] * f[j];
            }
        }
    }

    // LN(2048) per token
    float sv[4], qv[4];
#pragma unroll
    for (int ti = 0; ti < 4; ++ti) {
        float s = 0.f, q = 0.f;
#pragma unroll
        for (int j = 0; j < 8; ++j) { s += acc[ti][j]; q += acc[ti][j] * acc[ti][j]; }
        sv[ti] = wsum(s); qv[ti] = wsum(q);
    }
    __shared__ float red[4][4][2];
    const int wid = threadIdx.x >> 6, lane = threadIdx.x & 63;
    if (lane == 0)
#pragma unroll
        for (int ti = 0; ti < 4; ++ti) { red[wid][ti][0] = sv[ti]; red[wid][ti][1] = qv[ti]; }
    __syncthreads();

    f32x4 ga = *(const f32x4*)(g1 + ch), gb = *(const f32x4*)(g1 + ch + 4);
    f32x4 ba = *(const f32x4*)(b1 + ch), bb = *(const f32x4*)(b1 + ch + 4);
    float gg[8], bb8[8];
#pragma unroll
    for (int j = 0; j < 4; ++j) { gg[j] = ga[j]; gg[j + 4] = gb[j]; bb8[j] = ba[j]; bb8[j + 4] = bb[j]; }

#pragma unroll
    for (int ti = 0; ti < 4; ++ti) {
        const float s = red[0][ti][0] + red[1][ti][0] + red[2][ti][0] + red[3][ti][0];
        const float q = red[0][ti][1] + red[1][ti][1] + red[2][ti][1] + red[3][ti][1];
        const float mean = s * (1.0f / 2048), var = q * (1.0f / 2048) - mean * mean;
        const float rstd = rsqrtf(var + 1e-5f);
        bh8 o;
#pragma unroll
        for (int j = 0; j < 8; ++j) {
            float y = (acc[ti][j] - mean) * rstd * gg[j] + bb8[j];
            o[j] = f2bf(0.5f * y * (1.0f + erff(y * 0.70710678118654752f)));
        }
        *(bh8*)(ax + (s0 + ti) * HIDD + ch) = o;
    }
}

// ---------------------------------------------------------------- launch
extern "C" void kernel_launch(void* const* d_in, const int* in_sizes, int n_in,
                              void* d_out, int out_size, void* d_ws, size_t ws_size,
                              hipStream_t stream) {
    const float* x     = (const float*)d_in[0];
    const float* Wq    = (const float*)d_in[1];
    const float* bq    = (const float*)d_in[2];
    const float* Wk    = (const float*)d_in[3];
    const float* bk    = (const float*)d_in[4];
    const float* Wv    = (const float*)d_in[5];
    const float* bv    = (const float*)d_in[6];
    const float* scale = (const float*)d_in[7];
    const float* fc1_w = (const float*)d_in[8];
    const float* fc1_b = (const float*)d_in[9];
    const float* dw_w  = (const float*)d_in[10];
    const float* dw_b  = (const float*)d_in[11];
    const float* fc2_w = (const float*)d_in[12];
    const float* fc2_b = (const float*)d_in[13];
    const float* ln1_g = (const float*)d_in[14];
    const float* ln1_b = (const float*)d_in[15];
    const float* lnm_g = (const float*)d_in[16];
    const float* lnm_b = (const float*)d_in[17];
    float* out = (float*)d_out;
    char* p = (char*)d_ws;

    // ---- workspace layout ----
    // p+0      : xbT (32 MiB, bf16 (N,C)) — alive through EP_ATTN (shortcut source)
    // p+33M    : kb (conv-k; dead after splitk) -> then qb -> then axbuf
    // p+67M    : vb (conv-v; dead after splitk) -> then tbuf
    // d_out    : qe bf16 [0:32M] + splitk partials bf16 [32M:48M] -> enhanced f32 (full)
    bf16*  xbT   = (bf16*)(p + 0);
    bf16*  kb    = (bf16*)(p + 33554432);
    bf16*  vb    = (bf16*)(p + 67108864);
    bf16*  kvt   = (bf16*)(p + 100663296);    //  4 MiB: kv^T (B,512,512)
    bf16*  wqb   = (bf16*)(p + 104857600);
    bf16*  wkb   = (bf16*)(p + 105381888);
    bf16*  wvb   = (bf16*)(p + 105906176);
    bf16*  fc1wT = (bf16*)(p + 106430464);    //  2 MiB
    bf16*  fc2wT = (bf16*)(p + 108527616);    //  2 MiB
    float* invsc = (float*)(p + 110624768);
    float* dwwT  = (float*)(p + 110626816);   // 73,728 B
    float* qsum  = (float*)(p + 110757888);
    float* ksum  = (float*)(p + 110905344);
    float* zbuf  = (float*)(p + 110921728);
    const size_t REQUIRED = 111052800;
    // overlays: qpart/kpart live in the kvt region (dead until kvred writes kvt)
    float* qpart = (float*)kvt;               // 262,144 B
    float* kpart = (float*)((char*)kvt + 262144);   // 262,144 B
    bf16*  qe    = (bf16*)out;                        // 32 MiB
    bf16*  kvpart= (bf16*)((char*)out + 33554432);    // 16 MiB bf16 partials
    bf16*  qb    = kb;                        // after splitk, kb dead
    // FFN-phase overlays:
    bf16*  abuf  = (bf16*)(p + 0);            // xbT dead after attn (32 MiB)
    bf16*  axbuf = (bf16*)(p + 33554432);     // qb dead after attn (32 MiB)
    bf16*  tbuf  = (bf16*)(p + 67108864);     // vb dead after splitk (32 MiB)

    if (ws_size < REQUIRED) {   // sentinel encodes actual ws size in MiB
        k_fill<<<(out_size + 255) / 256, 256, 0, stream>>>(out, out_size, 100000.0f + (float)(ws_size >> 20));
        return;
    }

    const long NC = (long)NDIM * CDIM;  // 2,097,152 elements per batch

    // pack / convert params
    k_cvt3<<<1024, 256, 0, stream>>>(Wq, Wk, Wv, wqb, wkb, wvb);
    k_transpose<<<dim3(32, 8, 1), 256, 0, stream>>>(fc1_w, fc1wT, 2048, 512, 0, 0);
    k_transpose<<<dim3(8, 32, 1), 256, 0, stream>>>(fc2_w, fc2wT, 512, 2048, 0, 0);
    k_prep<<<72, 256, 0, stream>>>(scale, invsc, dw_w, dwwT);
    k_transpose<<<dim3(64, 8, BATCH), 256, 0, stream>>>(x, xbT, 4096, 512, NC, NC);

    // conv1x1 GEMMs: flat (C,N) out == raw (B,N,C) view
    gemm_bt<EP_QEXP, 128><<<dim3(32, 4, 8), 256, 0, stream>>>(wqb, 512, 0, xbT, 512, NC, qe, 4096, NC, 512, bq, nullptr, 0, nullptr, 0);
    gemm_bt<EP_BF16_BROW, 128><<<dim3(32, 4, 8), 256, 0, stream>>>(wkb, 512, 0, xbT, 512, NC, kb, 4096, NC, 512, bk, nullptr, 0, nullptr, 0);
    gemm_bt<EP_BF16_BROW, 128><<<dim3(32, 4, 8), 256, 0, stream>>>(wvb, 512, 0, xbT, 512, NC, vb, 4096, NC, 512, bv, nullptr, 0, nullptr, 0);

    // softmax denominators (both column chains), then combined reduce
    k_qcol_partial<<<dim3(2, 16, 8), 256, 0, stream>>>(qe, qpart);
    k_krow<<<8192, 256, 0, stream>>>(kb, invsc);
    k_colsum_part<<<dim3(16, 8), 256, 0, stream>>>(kb, kpart);
    k_red2<<<32, 256, 0, stream>>>(qpart, qsum, kpart, ksum);

    // kv^T — split-K x4, bf16 partials in out[32M:48M] (qe untouched)
    gemm_tn_splitk<<<dim3(4, 4, 32), 256, 0, stream>>>(vb, 512, NC, kb, 512, NC, kvpart);
    k_kvred<<<1024, 256, 0, stream>>>(kvpart, kvt);

    // q chain (after splitk so qb can overlay kb) + fused z
    k_qrow<<<8192, 256, 0, stream>>>(qe, qsum, invsc, qb, ksum, zbuf);

    // enhanced = bf16(shortcut from xbT) + z*(q@kv)  -> overwrites all of `out`
    gemm_bt<EP_ATTN, 128><<<dim3(4, 32, 8), 256, 0, stream>>>(qb, 512, NC, kvt, 512, 262144, out, 512, NC, 512, nullptr, xbT, NC, zbuf, 4096);

    // MixFFN: LN once over all rows, then 4 quarters over dead buffers
    k_ln512<<<8192, 256, 0, stream>>>(out, lnm_g, lnm_b, tbuf);
    for (int q4 = 0; q4 < 4; ++q4) {
        float* outq = out + (long)q4 * 8192 * CDIM;
        bf16* tq = tbuf + (long)q4 * 8192 * CDIM;
        gemm_bt<EP_BF16_BCOL, 128><<<dim3(16, 64, 1), 256, 0, stream>>>(tq, 512, 0, fc1wT, 512, 0, abuf, 2048, 0, 512, fc1_b, nullptr, 0, nullptr, 0);
        k_dwlngelu4<<<2048, 256, 0, stream>>>(abuf, dwwT, dw_b, ln1_g, ln1_b, axbuf);
        // fc2: 64x128 tile -> 512 blocks (2/CU) to keep co-resident overlap
        gemm_bt<EP_OUT, 64><<<dim3(4, 128, 1), 256, 0, stream>>>(axbuf, 2048, 0, fc2wT, 2048, 0, outq, 512, 0, 2048, fc2_b, outq, 0, nullptr, 0);
    }
}